// Round 1
// baseline (8402.542 us; speedup 1.0000x reference)
//
#include <hip/hip_runtime.h>

#define T_LEN   16384
#define B_SZ    4
#define AUDIO_C 256
#define RES_C   64
#define FG_C    64
#define SKIP_C  256
#define L_LAYERS 20

// ---------------- repack: make all weight reads consecutive+uniform ----------------
// pfg[i][c][o][4] = {filt_w[i][o][c][0], filt_w[i][o][c][1], gate_w[i][o][c][0], gate_w[i][o][c][1]}
// preT[c][o]  = pre_w[o][c]      (256 x 64)
// pp1T[c][p]  = pp1_w[p][c]      (256 x 256)
// pp2T[c][a]  = pp2_w[a][c]      (256 x 256)
__global__ __launch_bounds__(256) void repack_kernel(
    const float* __restrict__ fw, const float* __restrict__ gw,
    const float* __restrict__ prw, const float* __restrict__ p1, const float* __restrict__ p2,
    float* __restrict__ pfg, float* __restrict__ preT,
    float* __restrict__ pp1T, float* __restrict__ pp2T)
{
    int idx = blockIdx.x * 256 + threadIdx.x;
    const int NFG = L_LAYERS * 64 * 64;             // 81920
    if (idx < NFG) {
        int i = idx >> 12;
        int r = idx & 4095;
        int c = r >> 6, o = r & 63;
        int src = ((i * 64 + o) * 64 + c) * 2;
        float* dst = pfg + (((i * 64 + c) * 64) + o) * 4;
        dst[0] = fw[src];     dst[1] = fw[src + 1];
        dst[2] = gw[src];     dst[3] = gw[src + 1];
        return;
    }
    idx -= NFG;
    if (idx < 256 * 64) {                            // preT
        int c = idx >> 6, o = idx & 63;
        preT[c * 64 + o] = prw[o * 256 + c];
        return;
    }
    idx -= 256 * 64;
    if (idx < 256 * 256) {                           // pp1T
        int c = idx >> 8, p = idx & 255;
        pp1T[c * 256 + p] = p1[p * 256 + c];
        return;
    }
    idx -= 256 * 256;
    if (idx < 256 * 256) {                           // pp2T
        int c = idx >> 8, a = idx & 255;
        pp2T[c * 256 + a] = p2[a * 256 + c];
        return;
    }
}

// ---------------- pre: h0 = pre_w @ x + pre_b ----------------
__global__ __launch_bounds__(256) void pre_kernel(
    const float* __restrict__ x, const float* __restrict__ preT,
    const float* __restrict__ pre_b, float* __restrict__ h0)
{
    int g = blockIdx.x * 256 + threadIdx.x;
    int b = g >> 14, t = g & (T_LEN - 1);
    const float* xb = x + (size_t)b * AUDIO_C * T_LEN + t;
    float acc[RES_C];
#pragma unroll
    for (int o = 0; o < RES_C; ++o) acc[o] = 0.f;
    for (int c = 0; c < AUDIO_C; ++c) {
        float xv = xb[c * T_LEN];
        const float* w = preT + c * RES_C;
#pragma unroll
        for (int o = 0; o < RES_C; ++o) acc[o] += w[o] * xv;
    }
    float* hb = h0 + (size_t)b * RES_C * T_LEN + t;
#pragma unroll
    for (int o = 0; o < RES_C; ++o) hb[o * T_LEN] = acc[o] + pre_b[o];
}

// ---------------- fused gated layer ----------------
__global__ __launch_bounds__(256) void layer_kernel(
    const float* __restrict__ h_in, float* __restrict__ h_out,
    float* __restrict__ skip_sum,
    const float* __restrict__ pfg,      // this layer's packed [c][o][4]
    const float* __restrict__ fb, const float* __restrict__ gb,
    const float* __restrict__ sw, const float* __restrict__ sb,
    const float* __restrict__ rw, const float* __restrict__ rb,
    int d, int first)
{
    int g = blockIdx.x * 256 + threadIdx.x;
    int b = g >> 14, t = g & (T_LEN - 1);
    const float* hb = h_in + (size_t)b * RES_C * T_LEN + t;
    bool has_prev = (t >= d);
    int off_prev = has_prev ? -d : 0;    // always in-bounds address

    float accf[FG_C], accg[FG_C];
#pragma unroll
    for (int o = 0; o < FG_C; ++o) { accf[o] = fb[o]; accg[o] = gb[o]; }

    for (int c = 0; c < RES_C; ++c) {
        float hc = hb[c * T_LEN];
        float hpv = hb[c * T_LEN + off_prev];
        float hp = has_prev ? hpv : 0.f;
        const float* w = pfg + c * FG_C * 4;
#pragma unroll
        for (int o = 0; o < FG_C; ++o) {
            accf[o] += w[o * 4 + 0] * hp;
            accf[o] += w[o * 4 + 1] * hc;
            accg[o] += w[o * 4 + 2] * hp;
            accg[o] += w[o * 4 + 3] * hc;
        }
    }

    float z[FG_C];
#pragma unroll
    for (int o = 0; o < FG_C; ++o) {
        float ef = __expf(2.f * accf[o]);
        float th = 1.f - 2.f * __builtin_amdgcn_rcpf(ef + 1.f);
        float sg = __builtin_amdgcn_rcpf(1.f + __expf(-accg[o]));
        z[o] = th * sg;
    }

    // skip accumulation (global RMW, unique (b,p,t) per thread)
    float* sp = skip_sum + (size_t)b * SKIP_C * T_LEN + t;
    for (int p = 0; p < SKIP_C; p += 2) {
        float a0 = sb[p], a1 = sb[p + 1];
        const float* w0 = sw + p * FG_C;
        const float* w1 = sw + (p + 1) * FG_C;
#pragma unroll
        for (int o = 0; o < FG_C; ++o) {
            a0 += w0[o] * z[o];
            a1 += w1[o] * z[o];
        }
        if (first) {
            sp[p * T_LEN] = a0;
            sp[(p + 1) * T_LEN] = a1;
        } else {
            sp[p * T_LEN] += a0;
            sp[(p + 1) * T_LEN] += a1;
        }
    }

    // residual stream
    float* ho = h_out + (size_t)b * RES_C * T_LEN + t;
    for (int o = 0; o < RES_C; o += 2) {
        float a0 = rb[o] + hb[o * T_LEN];
        float a1 = rb[o + 1] + hb[(o + 1) * T_LEN];
        const float* w0 = rw + o * FG_C;
        const float* w1 = rw + (o + 1) * FG_C;
#pragma unroll
        for (int c2 = 0; c2 < FG_C; ++c2) {
            a0 += w0[c2] * z[c2];
            a1 += w1[c2] * z[c2];
        }
        ho[o * T_LEN] = a0;
        ho[(o + 1) * T_LEN] = a1;
    }
}

// ---------------- post: out = pp2 @ relu(pp1 @ relu(skip) + b1) + b2 ----------------
__global__ __launch_bounds__(256) void post_kernel(
    const float* __restrict__ skip_sum,
    const float* __restrict__ pp1T, const float* __restrict__ pp1_b,
    const float* __restrict__ pp2T, const float* __restrict__ pp2_b,
    float* __restrict__ out)
{
    __shared__ float lds[SKIP_C][64];   // 64 KB, reused for relu(skip) then relu(u)
    int tid = threadIdx.x;
    int q = tid >> 6, tt = tid & 63;
    int nb_t = T_LEN / 64;
    int b = blockIdx.x / nb_t;
    int t0 = (blockIdx.x % nb_t) * 64;

    const float* sp = skip_sum + (size_t)b * SKIP_C * T_LEN + t0;
#pragma unroll
    for (int j = 0; j < 64; ++j) {
        int c = q * 64 + j;
        float v = sp[c * T_LEN + tt];
        lds[c][tt] = v > 0.f ? v : 0.f;
    }
    __syncthreads();

    float u[64];
#pragma unroll
    for (int j = 0; j < 64; ++j) u[j] = pp1_b[q * 64 + j];
    for (int c = 0; c < SKIP_C; ++c) {
        float s = lds[c][tt];
        const float* w = pp1T + c * SKIP_C + q * 64;
#pragma unroll
        for (int j = 0; j < 64; ++j) u[j] += w[j] * s;
    }
    __syncthreads();
#pragma unroll
    for (int j = 0; j < 64; ++j) lds[q * 64 + j][tt] = u[j] > 0.f ? u[j] : 0.f;
    __syncthreads();

    float v[64];
#pragma unroll
    for (int j = 0; j < 64; ++j) v[j] = pp2_b[q * 64 + j];
    for (int c = 0; c < SKIP_C; ++c) {
        float s = lds[c][tt];
        const float* w = pp2T + c * AUDIO_C + q * 64;
#pragma unroll
        for (int j = 0; j < 64; ++j) v[j] += w[j] * s;
    }
    float* op = out + (size_t)b * AUDIO_C * T_LEN + t0;
#pragma unroll
    for (int j = 0; j < 64; ++j) op[(q * 64 + j) * T_LEN + tt] = v[j];
}

// ---------------- launch ----------------
extern "C" void kernel_launch(void* const* d_in, const int* in_sizes, int n_in,
                              void* d_out, int out_size, void* d_ws, size_t ws_size,
                              hipStream_t stream)
{
    const float* x      = (const float*)d_in[0];
    const float* pre_w  = (const float*)d_in[1];
    const float* pre_b  = (const float*)d_in[2];
    const float* filt_w = (const float*)d_in[3];
    const float* filt_b = (const float*)d_in[4];
    const float* gate_w = (const float*)d_in[5];
    const float* gate_b = (const float*)d_in[6];
    const float* res_w  = (const float*)d_in[7];
    const float* res_b  = (const float*)d_in[8];
    const float* skip_w = (const float*)d_in[9];
    const float* skip_b = (const float*)d_in[10];
    const float* pp1_w  = (const float*)d_in[11];
    const float* pp1_b  = (const float*)d_in[12];
    const float* pp2_w  = (const float*)d_in[13];
    const float* pp2_b  = (const float*)d_in[14];
    float* outp = (float*)d_out;

    // ws layout (floats)
    float* ws   = (float*)d_ws;
    float* skip = ws;                           // B*SKIP_C*T = 16777216
    float* pfg  = ws + (size_t)16777216;        // 20*64*64*4 = 327680
    float* preT = pfg + 327680;                 // 16384
    float* pp1T = preT + 16384;                 // 65536
    float* pp2T = pp1T + 65536;                 // 65536

    // h ping-pong inside d_out (B*RES_C*T = 4194304 floats each; d_out holds 16777216)
    float* h0 = outp;
    float* h1 = outp + (size_t)B_SZ * RES_C * T_LEN;

    repack_kernel<<<896, 256, 0, stream>>>(filt_w, gate_w, pre_w, pp1_w, pp2_w,
                                           pfg, preT, pp1T, pp2T);

    pre_kernel<<<(B_SZ * T_LEN) / 256, 256, 0, stream>>>(x, preT, pre_b, h0);

    const float* hin = h0;
    float* hout = h1;
    for (int i = 0; i < L_LAYERS; ++i) {
        int d = 1 << (i % 10);
        layer_kernel<<<(B_SZ * T_LEN) / 256, 256, 0, stream>>>(
            hin, hout, skip,
            pfg + (size_t)i * 64 * 64 * 4,
            filt_b + i * FG_C, gate_b + i * FG_C,
            skip_w + (size_t)i * SKIP_C * FG_C, skip_b + i * SKIP_C,
            res_w + (size_t)i * RES_C * FG_C, res_b + i * RES_C,
            d, (i == 0) ? 1 : 0);
        const float* tmp = hin; hin = hout; hout = (float*)tmp;
    }

    post_kernel<<<B_SZ * (T_LEN / 64), 256, 0, stream>>>(skip, pp1T, pp1_b, pp2T, pp2_b, outp);
}

// Round 2
// 634.537 us; speedup vs baseline: 13.2420x; 13.2420x over previous
//
#include <hip/hip_runtime.h>

#define T_LEN   16384
#define B_SZ    4
#define AUDIO_C 256
#define RES_C   64
#define SKIP_C  256
#define L_LAYERS 20

typedef unsigned short u16;
using bf16x8 = __attribute__((ext_vector_type(8))) __bf16;
using f32x4  = __attribute__((ext_vector_type(4))) float;

__device__ __forceinline__ u16 f2bf(float x){
    union { float f; unsigned u; } v; v.f = x;
    return (u16)((v.u + 0x7FFFu + ((v.u >> 16) & 1u)) >> 16);
}
__device__ __forceinline__ unsigned packbf(float a, float b){
    return (unsigned)f2bf(a) | ((unsigned)f2bf(b) << 16);
}
__device__ __forceinline__ f32x4 mfma16(uint4 a, uint4 b, f32x4 c){
    return __builtin_amdgcn_mfma_f32_16x16x32_bf16(
        __builtin_bit_cast(bf16x8, a), __builtin_bit_cast(bf16x8, b), c, 0, 0, 0);
}

// ================= repack: weights -> per-lane MFMA A-fragments (bf16) =================
// w1p  [L][mt0..7][kk0..3][lane][8]   GEMM1 A (filt rows 0..63, gate rows 64..127), K=128
// swp  [L][mt0..15][kk0..1][lane][8]  skip A, K=64
// rwp  [L][mt0..3][kk0..1][lane][8]   res A,  K=64
// pp1p [mt0..15][kk0..7][lane][8]     pp1 A,  K=256
// pp2p [mt0..15][kk0..7][lane][8]     pp2 A,  K=256
// preT [c][o] fp32 ; sbsum[p] = sum_i skip_b[i][p]
__global__ __launch_bounds__(256) void repack2(
    const float* __restrict__ fw, const float* __restrict__ gw,
    const float* __restrict__ sw, const float* __restrict__ rw,
    const float* __restrict__ p1, const float* __restrict__ p2,
    const float* __restrict__ prw, const float* __restrict__ sb,
    u16* __restrict__ w1p, u16* __restrict__ swp, u16* __restrict__ rwp,
    u16* __restrict__ pp1p, u16* __restrict__ pp2p,
    float* __restrict__ preT, float* __restrict__ sbsum)
{
    int idx = blockIdx.x * 256 + threadIdx.x;
    if (idx < 327680) {                             // w1p: L * 2^14
        int j = idx & 7, l = (idx >> 3) & 63, kk = (idx >> 9) & 3, mt = (idx >> 11) & 7, i = idx >> 14;
        int m = mt * 16 + (l & 15);
        int k = kk * 32 + (l >> 4) * 8 + j;
        const float* srcw = (m < 64) ? fw : gw;
        int mm = m & 63, c = k & 63, tap = k >> 6;
        w1p[idx] = f2bf(srcw[((i * 64 + mm) * 64 + c) * 2 + tap]);
        return;
    }
    idx -= 327680;
    if (idx < 327680) {                             // swp: L * 2^14
        int j = idx & 7, l = (idx >> 3) & 63, kk = (idx >> 9) & 1, mt = (idx >> 10) & 15, i = idx >> 14;
        int p = mt * 16 + (l & 15);
        int c = kk * 32 + (l >> 4) * 8 + j;
        swp[idx] = f2bf(sw[(i * 256 + p) * 64 + c]);
        return;
    }
    idx -= 327680;
    if (idx < 81920) {                              // rwp: L * 2^12
        int j = idx & 7, l = (idx >> 3) & 63, kk = (idx >> 9) & 1, mt = (idx >> 10) & 3, i = idx >> 12;
        int o = mt * 16 + (l & 15);
        int c = kk * 32 + (l >> 4) * 8 + j;
        rwp[idx] = f2bf(rw[(i * 64 + o) * 64 + c]);
        return;
    }
    idx -= 81920;
    if (idx < 65536) {                              // pp1p
        int j = idx & 7, l = (idx >> 3) & 63, kk = (idx >> 9) & 7, mt = idx >> 12;
        int m = mt * 16 + (l & 15);
        int k = kk * 32 + (l >> 4) * 8 + j;
        pp1p[idx] = f2bf(p1[m * 256 + k]);
        return;
    }
    idx -= 65536;
    if (idx < 65536) {                              // pp2p
        int j = idx & 7, l = (idx >> 3) & 63, kk = (idx >> 9) & 7, mt = idx >> 12;
        int m = mt * 16 + (l & 15);
        int k = kk * 32 + (l >> 4) * 8 + j;
        pp2p[idx] = f2bf(p2[m * 256 + k]);
        return;
    }
    idx -= 65536;
    if (idx < 16384) {                              // preT
        int c = idx >> 6, o = idx & 63;
        preT[idx] = prw[o * 256 + c];
        return;
    }
    idx -= 16384;
    if (idx < 256) {                                // sbsum
        float s = 0.f;
        for (int i = 0; i < L_LAYERS; ++i) s += sb[i * 256 + idx];
        sbsum[idx] = s;
        return;
    }
}

// ================= pre: h0 = pre_w @ x + pre_b (fp32 VALU, 4-way o-split) ==============
__global__ __launch_bounds__(256) void pre_kernel(
    const float* __restrict__ x, const float* __restrict__ preT,
    const float* __restrict__ pre_b, float* __restrict__ h0, u16* __restrict__ hb0)
{
    int g = blockIdx.x * 256 + threadIdx.x;        // 262144 threads
    int t = g & (T_LEN - 1);
    int b = (g >> 14) & 3;
    int og = g >> 16;                               // 0..3 -> 16 outputs each
    const float* xb = x + (size_t)b * AUDIO_C * T_LEN + t;
    float acc[16];
#pragma unroll
    for (int o = 0; o < 16; ++o) acc[o] = 0.f;
    for (int c = 0; c < AUDIO_C; ++c) {
        float xv = xb[c * T_LEN];
        const float* w = preT + c * RES_C + og * 16;
#pragma unroll
        for (int o = 0; o < 16; ++o) acc[o] += w[o] * xv;
    }
#pragma unroll
    for (int o = 0; o < 16; ++o) acc[o] += pre_b[og * 16 + o];
    float* hb = h0 + (size_t)b * RES_C * T_LEN + t;
#pragma unroll
    for (int o = 0; o < 16; ++o) hb[(og * 16 + o) * T_LEN] = acc[o];
    u16* ho = hb0 + ((size_t)b * T_LEN + t) * 64 + og * 16;
#pragma unroll
    for (int o = 0; o < 16; o += 2)
        *(unsigned*)(ho + o) = packbf(acc[o], acc[o + 1]);
}

// ================= fused gated layer (MFMA) =================
// block: 256 thr (4 waves), t-tile = 64.  wave w: GEMM1 m-tiles {w (filt), w+4 (gate)},
// res m-tile w, (plan C) skip m-tiles {4w..4w+3}.
template<int DO_SKIP>
__global__ __launch_bounds__(256) void layer_mfma(
    const float* __restrict__ hin, float* __restrict__ hout,
    const u16* __restrict__ hbin, u16* __restrict__ hbout,
    u16* __restrict__ zTi, float* __restrict__ skipsum,
    const u16* __restrict__ w1p, const u16* __restrict__ swp, const u16* __restrict__ rwp,
    const float* __restrict__ fb, const float* __restrict__ gb,
    const float* __restrict__ sb, const float* __restrict__ rb,
    int d, int first)
{
    __shared__ u16 zl[64 * 64];
    int tid = threadIdx.x;
    int w = tid >> 6, l = tid & 63;
    int lo = l & 15, hi = l >> 4;
    int nblk = T_LEN / 64;
    int b = blockIdx.x / nblk, t0 = (blockIdx.x % nblk) * 64;

    // ---- phase 1: GEMM1 (f,g) ----
    const uint4* w1v = (const uint4*)w1p;
    uint4 aF[4], aG[4];
#pragma unroll
    for (int kk = 0; kk < 4; ++kk) {
        aF[kk] = w1v[(w * 4 + kk) * 64 + l];
        aG[kk] = w1v[((w + 4) * 4 + kk) * 64 + l];
    }
    f32x4 accF[4], accG[4];
    {
        f32x4 iF, iG;
#pragma unroll
        for (int r = 0; r < 4; ++r) { iF[r] = fb[w * 16 + hi * 4 + r]; iG[r] = gb[w * 16 + hi * 4 + r]; }
#pragma unroll
        for (int nt = 0; nt < 4; ++nt) { accF[nt] = iF; accG[nt] = iG; }
    }
    const u16* hb = hbin + (size_t)b * T_LEN * 64;
#pragma unroll
    for (int nt = 0; nt < 4; ++nt) {
        int tc = t0 + nt * 16 + lo;
#pragma unroll
        for (int kk = 0; kk < 4; ++kk) {
            int tap = kk >> 1;
            int c0 = (kk & 1) * 32 + hi * 8;
            int tt = tap ? tc : tc - d;
            int tcl = tt < 0 ? 0 : tt;
            uint4 bv = *(const uint4*)(hb + (size_t)tcl * 64 + c0);
            if (tt < 0) bv = make_uint4(0u, 0u, 0u, 0u);
            accF[nt] = mfma16(aF[kk], bv, accF[nt]);
            accG[nt] = mfma16(aG[kk], bv, accG[nt]);
        }
    }

    // ---- activation + z staging (LDS swizzled, optionally z -> global t-major) ----
#pragma unroll
    for (int nt = 0; nt < 4; ++nt) {
        float zv[4];
#pragma unroll
        for (int r = 0; r < 4; ++r) {
            float f = accF[nt][r], g = accG[nt][r];
            float ef = __expf(2.f * f);
            float th = 1.f - 2.f * __builtin_amdgcn_rcpf(ef + 1.f);
            float sg = __builtin_amdgcn_rcpf(1.f + __expf(-g));
            zv[r] = th * sg;
        }
        int n = nt * 16 + lo;
        int k0 = w * 16 + hi * 4;
        int col = k0 ^ ((n & 7) << 3);
        unsigned p01 = packbf(zv[0], zv[1]);
        unsigned p23 = packbf(zv[2], zv[3]);
        *(unsigned*)(&zl[n * 64 + col]) = p01;
        *(unsigned*)(&zl[n * 64 + col + 2]) = p23;
        if (!DO_SKIP) {
            u16* zt = zTi + ((size_t)b * T_LEN + t0 + n) * 64 + k0;
            *(unsigned*)(zt) = p01;
            *(unsigned*)(zt + 2) = p23;
        }
    }
    __syncthreads();

    // ---- phase 2: res GEMM (+ skip GEMM for plan C) ----
    const uint4* rwv = (const uint4*)rwp;
    uint4 aR[2];
    aR[0] = rwv[(w * 2 + 0) * 64 + l];
    aR[1] = rwv[(w * 2 + 1) * 64 + l];
    f32x4 accR[4];
    {
        f32x4 iR;
#pragma unroll
        for (int r = 0; r < 4; ++r) iR[r] = rb[w * 16 + hi * 4 + r];
#pragma unroll
        for (int nt = 0; nt < 4; ++nt) accR[nt] = iR;
    }
    uint4 aS[4][2];
    f32x4 accS[4][4];
    if (DO_SKIP) {
        const uint4* swv = (const uint4*)swp;
#pragma unroll
        for (int mi = 0; mi < 4; ++mi) {
            aS[mi][0] = swv[((w * 4 + mi) * 2 + 0) * 64 + l];
            aS[mi][1] = swv[((w * 4 + mi) * 2 + 1) * 64 + l];
            f32x4 iS;
#pragma unroll
            for (int r = 0; r < 4; ++r) iS[r] = sb[(w * 4 + mi) * 16 + hi * 4 + r];
#pragma unroll
            for (int nt = 0; nt < 4; ++nt) accS[mi][nt] = iS;
        }
    }
#pragma unroll
    for (int nt = 0; nt < 4; ++nt) {
        int n = nt * 16 + lo;
#pragma unroll
        for (int kk = 0; kk < 2; ++kk) {
            int kb = kk * 32 + hi * 8;
            uint4 bz = *(const uint4*)(&zl[n * 64 + (kb ^ ((n & 7) << 3))]);
            accR[nt] = mfma16(aR[kk], bz, accR[nt]);
            if (DO_SKIP) {
#pragma unroll
                for (int mi = 0; mi < 4; ++mi)
                    accS[mi][nt] = mfma16(aS[mi][kk], bz, accS[mi][nt]);
            }
        }
    }

    // ---- epilogue: h_out = h_in + res (fp32) + bf16 mirror ----
#pragma unroll
    for (int nt = 0; nt < 4; ++nt) {
        int t = t0 + nt * 16 + lo;
        int o0 = w * 16 + hi * 4;
        float hv[4];
#pragma unroll
        for (int r = 0; r < 4; ++r) {
            hv[r] = hin[((size_t)b * 64 + o0 + r) * T_LEN + t] + accR[nt][r];
            hout[((size_t)b * 64 + o0 + r) * T_LEN + t] = hv[r];
        }
        u16* hbo = hbout + ((size_t)b * T_LEN + t) * 64 + o0;
        *(unsigned*)(hbo) = packbf(hv[0], hv[1]);
        *(unsigned*)(hbo + 2) = packbf(hv[2], hv[3]);
    }
    if (DO_SKIP) {
#pragma unroll
        for (int mi = 0; mi < 4; ++mi) {
#pragma unroll
            for (int nt = 0; nt < 4; ++nt) {
                int t = t0 + nt * 16 + lo;
                int p0 = (w * 4 + mi) * 16 + hi * 4;
#pragma unroll
                for (int r = 0; r < 4; ++r) {
                    float* sp = &skipsum[((size_t)b * 256 + p0 + r) * T_LEN + t];
                    float v = accS[mi][nt][r];
                    if (first) *sp = v; else *sp = *sp + v;
                }
            }
        }
    }
}

// ================= post: skip-sum -> relu -> pp1 -> relu -> pp2 (MFMA) =================
template<int FROM_Z>
__global__ __launch_bounds__(256) void post_mfma(
    const u16* __restrict__ zT, const float* __restrict__ skipsum,
    const u16* __restrict__ swpAll, const float* __restrict__ sbsum,
    const u16* __restrict__ pp1p, const float* __restrict__ pp1b,
    const u16* __restrict__ pp2p, const float* __restrict__ pp2b,
    float* __restrict__ out)
{
    __shared__ u16 sl[64 * 256];
    int tid = threadIdx.x;
    int w = tid >> 6, l = tid & 63;
    int lo = l & 15, hi = l >> 4;
    int nblk = T_LEN / 64;
    int b = blockIdx.x / nblk, t0 = (blockIdx.x % nblk) * 64;

    // ---- stage s = relu(skip_sum) into sl ----
    if (FROM_Z) {
        f32x4 acc[4][4];
#pragma unroll
        for (int mi = 0; mi < 4; ++mi) {
            f32x4 iS;
#pragma unroll
            for (int r = 0; r < 4; ++r) iS[r] = sbsum[(w * 4 + mi) * 16 + hi * 4 + r];
#pragma unroll
            for (int nt = 0; nt < 4; ++nt) acc[mi][nt] = iS;
        }
        const uint4* swv = (const uint4*)swpAll;
        for (int i = 0; i < L_LAYERS; ++i) {
            const u16* zb = zT + ((size_t)i * 4 + b) * T_LEN * 64;
#pragma unroll
            for (int kk = 0; kk < 2; ++kk) {
                uint4 a[4];
#pragma unroll
                for (int mi = 0; mi < 4; ++mi)
                    a[mi] = swv[((i * 16 + w * 4 + mi) * 2 + kk) * 64 + l];
#pragma unroll
                for (int nt = 0; nt < 4; ++nt) {
                    uint4 bz = *(const uint4*)(zb + ((size_t)(t0 + nt * 16 + lo)) * 64 + kk * 32 + hi * 8);
#pragma unroll
                    for (int mi = 0; mi < 4; ++mi)
                        acc[mi][nt] = mfma16(a[mi], bz, acc[mi][nt]);
                }
            }
        }
#pragma unroll
        for (int mi = 0; mi < 4; ++mi) {
#pragma unroll
            for (int nt = 0; nt < 4; ++nt) {
                int n = nt * 16 + lo;
                int k0 = (w * 4 + mi) * 16 + hi * 4;
                int col = k0 ^ ((n & 15) << 3);
                float v0 = acc[mi][nt][0], v1 = acc[mi][nt][1], v2 = acc[mi][nt][2], v3 = acc[mi][nt][3];
                v0 = v0 > 0.f ? v0 : 0.f; v1 = v1 > 0.f ? v1 : 0.f;
                v2 = v2 > 0.f ? v2 : 0.f; v3 = v3 > 0.f ? v3 : 0.f;
                *(unsigned*)(&sl[n * 256 + col]) = packbf(v0, v1);
                *(unsigned*)(&sl[n * 256 + col + 2]) = packbf(v2, v3);
            }
        }
    } else {
#pragma unroll
        for (int mi = 0; mi < 4; ++mi) {
#pragma unroll
            for (int nt = 0; nt < 4; ++nt) {
                int n = nt * 16 + lo;
                int t = t0 + n;
                int p0 = (w * 4 + mi) * 16 + hi * 4;
                float v[4];
#pragma unroll
                for (int r = 0; r < 4; ++r) {
                    float s = skipsum[((size_t)b * 256 + p0 + r) * T_LEN + t];
                    v[r] = s > 0.f ? s : 0.f;
                }
                int col = p0 ^ ((n & 15) << 3);
                *(unsigned*)(&sl[n * 256 + col]) = packbf(v[0], v[1]);
                *(unsigned*)(&sl[n * 256 + col + 2]) = packbf(v[2], v[3]);
            }
        }
    }
    __syncthreads();

    // ---- pp1 ----
    f32x4 u[4][4];
#pragma unroll
    for (int mi = 0; mi < 4; ++mi) {
        f32x4 iU;
#pragma unroll
        for (int r = 0; r < 4; ++r) iU[r] = pp1b[(w * 4 + mi) * 16 + hi * 4 + r];
#pragma unroll
        for (int nt = 0; nt < 4; ++nt) u[mi][nt] = iU;
    }
    {
        const uint4* p1v = (const uint4*)pp1p;
#pragma unroll
        for (int kk = 0; kk < 8; ++kk) {
            uint4 a[4];
#pragma unroll
            for (int mi = 0; mi < 4; ++mi)
                a[mi] = p1v[((w * 4 + mi) * 8 + kk) * 64 + l];
#pragma unroll
            for (int nt = 0; nt < 4; ++nt) {
                int n = nt * 16 + lo;
                int kb = kk * 32 + hi * 8;
                uint4 bz = *(const uint4*)(&sl[n * 256 + (kb ^ ((n & 15) << 3))]);
#pragma unroll
                for (int mi = 0; mi < 4; ++mi)
                    u[mi][nt] = mfma16(a[mi], bz, u[mi][nt]);
            }
        }
    }
    __syncthreads();
#pragma unroll
    for (int mi = 0; mi < 4; ++mi) {
#pragma unroll
        for (int nt = 0; nt < 4; ++nt) {
            int n = nt * 16 + lo;
            int k0 = (w * 4 + mi) * 16 + hi * 4;
            int col = k0 ^ ((n & 15) << 3);
            float v0 = u[mi][nt][0], v1 = u[mi][nt][1], v2 = u[mi][nt][2], v3 = u[mi][nt][3];
            v0 = v0 > 0.f ? v0 : 0.f; v1 = v1 > 0.f ? v1 : 0.f;
            v2 = v2 > 0.f ? v2 : 0.f; v3 = v3 > 0.f ? v3 : 0.f;
            *(unsigned*)(&sl[n * 256 + col]) = packbf(v0, v1);
            *(unsigned*)(&sl[n * 256 + col + 2]) = packbf(v2, v3);
        }
    }
    __syncthreads();

    // ---- pp2 ----
    f32x4 vv[4][4];
#pragma unroll
    for (int mi = 0; mi < 4; ++mi) {
        f32x4 iV;
#pragma unroll
        for (int r = 0; r < 4; ++r) iV[r] = pp2b[(w * 4 + mi) * 16 + hi * 4 + r];
#pragma unroll
        for (int nt = 0; nt < 4; ++nt) vv[mi][nt] = iV;
    }
    {
        const uint4* p2v = (const uint4*)pp2p;
#pragma unroll
        for (int kk = 0; kk < 8; ++kk) {
            uint4 a[4];
#pragma unroll
            for (int mi = 0; mi < 4; ++mi)
                a[mi] = p2v[((w * 4 + mi) * 8 + kk) * 64 + l];
#pragma unroll
            for (int nt = 0; nt < 4; ++nt) {
                int n = nt * 16 + lo;
                int kb = kk * 32 + hi * 8;
                uint4 bz = *(const uint4*)(&sl[n * 256 + (kb ^ ((n & 15) << 3))]);
#pragma unroll
                for (int mi = 0; mi < 4; ++mi)
                    vv[mi][nt] = mfma16(a[mi], bz, vv[mi][nt]);
            }
        }
    }
#pragma unroll
    for (int mi = 0; mi < 4; ++mi) {
#pragma unroll
        for (int nt = 0; nt < 4; ++nt) {
            int t = t0 + nt * 16 + lo;
            int p0 = (w * 4 + mi) * 16 + hi * 4;
#pragma unroll
            for (int r = 0; r < 4; ++r)
                out[((size_t)b * 256 + p0 + r) * T_LEN + t] = vv[mi][nt][r];
        }
    }
}

// ================= launch =================
extern "C" void kernel_launch(void* const* d_in, const int* in_sizes, int n_in,
                              void* d_out, int out_size, void* d_ws, size_t ws_size,
                              hipStream_t stream)
{
    const float* x      = (const float*)d_in[0];
    const float* pre_w  = (const float*)d_in[1];
    const float* pre_b  = (const float*)d_in[2];
    const float* filt_w = (const float*)d_in[3];
    const float* filt_b = (const float*)d_in[4];
    const float* gate_w = (const float*)d_in[5];
    const float* gate_b = (const float*)d_in[6];
    const float* res_w  = (const float*)d_in[7];
    const float* res_b  = (const float*)d_in[8];
    const float* skip_w = (const float*)d_in[9];
    const float* skip_b = (const float*)d_in[10];
    const float* pp1_w  = (const float*)d_in[11];
    const float* pp1_b  = (const float*)d_in[12];
    const float* pp2_w  = (const float*)d_in[13];
    const float* pp2_b  = (const float*)d_in[14];
    float* outp = (float*)d_out;

    // d_out scratch: h fp32 ping-pong (2 x 16.8MB) + h bf16 t-major ping-pong (2 x 8.4MB)
    float* h0 = outp;
    float* h1 = outp + (size_t)4194304;
    u16*   hb0 = (u16*)(outp + (size_t)8388608);
    u16*   hb1 = hb0 + (size_t)4194304;

    const size_t ZT_BYTES   = (size_t)L_LAYERS * B_SZ * T_LEN * 64 * 2;  // 167,772,160
    const size_t SKIP_BYTES = (size_t)B_SZ * SKIP_C * T_LEN * 4;         // 67,108,864
    const bool planA = ws_size >= ZT_BYTES + (size_t)4 * 1024 * 1024;

    char* ws = (char*)d_ws;
    u16*   zT      = (u16*)ws;
    float* skipsum = (float*)ws;
    size_t packoff = planA ? ZT_BYTES : SKIP_BYTES;
    u16* w1p  = (u16*)(ws + packoff);
    u16* swp  = w1p + 327680;
    u16* rwp  = swp + 327680;
    u16* pp1p = rwp + 81920;
    u16* pp2p = pp1p + 65536;
    float* preT  = (float*)(pp2p + 65536);
    float* sbsum = preT + 16384;

    repack2<<<3457, 256, 0, stream>>>(filt_w, gate_w, skip_w, res_w, pp1_w, pp2_w, pre_w, skip_b,
                                      w1p, swp, rwp, pp1p, pp2p, preT, sbsum);

    pre_kernel<<<1024, 256, 0, stream>>>(x, preT, pre_b, h0, hb0);

    const float* hi_ = h0; float* ho_ = h1;
    const u16* hbi = hb0;  u16* hbo = hb1;
    for (int i = 0; i < L_LAYERS; ++i) {
        int d = 1 << (i % 10);
        if (planA)
            layer_mfma<0><<<1024, 256, 0, stream>>>(
                hi_, ho_, hbi, hbo,
                zT + (size_t)i * 4194304, skipsum,
                w1p + (size_t)i * 16384, swp + (size_t)i * 16384, rwp + (size_t)i * 4096,
                filt_b + i * 64, gate_b + i * 64, skip_b + i * 256, res_b + i * 64,
                d, (i == 0) ? 1 : 0);
        else
            layer_mfma<1><<<1024, 256, 0, stream>>>(
                hi_, ho_, hbi, hbo,
                zT, skipsum,
                w1p + (size_t)i * 16384, swp + (size_t)i * 16384, rwp + (size_t)i * 4096,
                filt_b + i * 64, gate_b + i * 64, skip_b + i * 256, res_b + i * 64,
                d, (i == 0) ? 1 : 0);
        { const float* tf = hi_; hi_ = ho_; ho_ = (float*)tf; }
        { const u16* tb = hbi; hbi = hbo; hbo = (u16*)tb; }
    }

    if (planA)
        post_mfma<1><<<1024, 256, 0, stream>>>(zT, skipsum, swp, sbsum,
                                               pp1p, pp1_b, pp2p, pp2_b, outp);
    else
        post_mfma<0><<<1024, 256, 0, stream>>>(zT, skipsum, swp, sbsum,
                                               pp1p, pp1_b, pp2p, pp2_b, outp);
}

// Round 3
// 600.573 us; speedup vs baseline: 13.9909x; 1.0566x over previous
//
#include <hip/hip_runtime.h>

#define T_LEN   16384
#define B_SZ    4
#define AUDIO_C 256
#define RES_C   64
#define SKIP_C  256
#define L_LAYERS 20

typedef unsigned short u16;
using bf16x8 = __attribute__((ext_vector_type(8))) __bf16;
using f32x4  = __attribute__((ext_vector_type(4))) float;

__device__ __forceinline__ u16 f2bf(float x){
    union { float f; unsigned u; } v; v.f = x;
    return (u16)((v.u + 0x7FFFu + ((v.u >> 16) & 1u)) >> 16);
}
// compiler-fused v_cvt_pk_bf16_f32 (a -> low 16, b -> high 16)
__device__ __forceinline__ unsigned cvt2(float a, float b){
    union { __bf16 h[2]; unsigned u; } r;
    r.h[0] = (__bf16)a; r.h[1] = (__bf16)b;
    return r.u;
}
__device__ __forceinline__ f32x4 mfma16(uint4 a, uint4 b, f32x4 c){
    return __builtin_amdgcn_mfma_f32_16x16x32_bf16(
        __builtin_bit_cast(bf16x8, a), __builtin_bit_cast(bf16x8, b), c, 0, 0, 0);
}

// ================= repack: weights -> per-lane MFMA A-fragments (bf16) =================
__global__ __launch_bounds__(256) void repack2(
    const float* __restrict__ fw, const float* __restrict__ gw,
    const float* __restrict__ sw, const float* __restrict__ rw,
    const float* __restrict__ p1, const float* __restrict__ p2,
    const float* __restrict__ prw, const float* __restrict__ sb,
    u16* __restrict__ w1p, u16* __restrict__ swp, u16* __restrict__ rwp,
    u16* __restrict__ pp1p, u16* __restrict__ pp2p,
    u16* __restrict__ prep, float* __restrict__ sbsum)
{
    int idx = blockIdx.x * 256 + threadIdx.x;
    if (idx < 327680) {                             // w1p: L * 2^14  (GEMM1 A, K=128)
        int j = idx & 7, l = (idx >> 3) & 63, kk = (idx >> 9) & 3, mt = (idx >> 11) & 7, i = idx >> 14;
        int m = mt * 16 + (l & 15);
        int k = kk * 32 + (l >> 4) * 8 + j;
        const float* srcw = (m < 64) ? fw : gw;
        int mm = m & 63, c = k & 63, tap = k >> 6;
        w1p[idx] = f2bf(srcw[((i * 64 + mm) * 64 + c) * 2 + tap]);
        return;
    }
    idx -= 327680;
    if (idx < 327680) {                             // swp: skip A, K=64
        int j = idx & 7, l = (idx >> 3) & 63, kk = (idx >> 9) & 1, mt = (idx >> 10) & 15, i = idx >> 14;
        int p = mt * 16 + (l & 15);
        int c = kk * 32 + (l >> 4) * 8 + j;
        swp[idx] = f2bf(sw[(i * 256 + p) * 64 + c]);
        return;
    }
    idx -= 327680;
    if (idx < 81920) {                              // rwp: res A, K=64
        int j = idx & 7, l = (idx >> 3) & 63, kk = (idx >> 9) & 1, mt = (idx >> 10) & 3, i = idx >> 12;
        int o = mt * 16 + (l & 15);
        int c = kk * 32 + (l >> 4) * 8 + j;
        rwp[idx] = f2bf(rw[(i * 64 + o) * 64 + c]);
        return;
    }
    idx -= 81920;
    if (idx < 65536) {                              // pp1p: K=256
        int j = idx & 7, l = (idx >> 3) & 63, kk = (idx >> 9) & 7, mt = idx >> 12;
        int m = mt * 16 + (l & 15);
        int k = kk * 32 + (l >> 4) * 8 + j;
        pp1p[idx] = f2bf(p1[m * 256 + k]);
        return;
    }
    idx -= 65536;
    if (idx < 65536) {                              // pp2p: K=256
        int j = idx & 7, l = (idx >> 3) & 63, kk = (idx >> 9) & 7, mt = idx >> 12;
        int m = mt * 16 + (l & 15);
        int k = kk * 32 + (l >> 4) * 8 + j;
        pp2p[idx] = f2bf(p2[m * 256 + k]);
        return;
    }
    idx -= 65536;
    if (idx < 16384) {                              // prep: pre A, M=64, K=256
        int j = idx & 7, l = (idx >> 3) & 63, kk = (idx >> 9) & 7, mt = idx >> 12;
        int m = mt * 16 + (l & 15);
        int k = kk * 32 + (l >> 4) * 8 + j;
        prep[idx] = f2bf(prw[m * 256 + k]);
        return;
    }
    idx -= 16384;
    if (idx < 256) {                                // sbsum[p] = sum_i skip_b[i][p]
        float s = 0.f;
        for (int i = 0; i < L_LAYERS; ++i) s += sb[i * 256 + idx];
        sbsum[idx] = s;
        return;
    }
}

// ================= pre (MFMA): ht[b][t][o] = pre_w @ x + pre_b ==================
// LDS transpose staging: sx holds x-tile bf16 [64 t][256 c], chunk(16B)-XOR swizzled.
__global__ __launch_bounds__(256) void pre_mfma(
    const float* __restrict__ x, const u16* __restrict__ prep,
    const float* __restrict__ pre_b, float* __restrict__ ht)
{
    __shared__ u16 sx[64 * 256];                    // 32 KB
    unsigned* sx32 = (unsigned*)sx;
    int tid = threadIdx.x;
    int w = tid >> 6, l = tid & 63;
    int lo = l & 15, hi = l >> 4;
    int nblk = T_LEN / 64;
    int b = blockIdx.x / nblk, t0 = (blockIdx.x % nblk) * 64;

    // ---- stage: thread (cgroup=w, t=l); wave-coalesced 256B rows of x ----
    {
        int t = l;
        const float* xb = x + (size_t)b * AUDIO_C * T_LEN + t0 + t;
#pragma unroll 8
        for (int c2 = 0; c2 < 64; c2 += 2) {
            int c = w * 64 + c2;
            float v0 = xb[(size_t)c * T_LEN];
            float v1 = xb[(size_t)(c + 1) * T_LEN];
            int ch = c >> 3;
            int a32 = t * 128 + ((ch ^ (t & 7)) << 2) + ((c >> 1) & 3);
            sx32[a32] = cvt2(v0, v1);
        }
    }
    __syncthreads();

    // ---- GEMM: wave w -> m-tile w (o=w*16..w*16+15), nt 0..3, K=256 ----
    const uint4* av = (const uint4*)prep;
    f32x4 acc[4];
    {
        f32x4 ib;
#pragma unroll
        for (int r = 0; r < 4; ++r) ib[r] = pre_b[w * 16 + hi * 4 + r];
#pragma unroll
        for (int nt = 0; nt < 4; ++nt) acc[nt] = ib;
    }
#pragma unroll
    for (int kk = 0; kk < 8; ++kk) {
        uint4 a = av[(w * 8 + kk) * 64 + l];
#pragma unroll
        for (int nt = 0; nt < 4; ++nt) {
            int t = nt * 16 + lo;
            int ch = kk * 4 + hi;
            uint4 bv = *(const uint4*)&sx32[t * 128 + ((ch ^ (t & 7)) << 2)];
            acc[nt] = mfma16(a, bv, acc[nt]);
        }
    }
#pragma unroll
    for (int nt = 0; nt < 4; ++nt) {
        int t = t0 + nt * 16 + lo;
        *(f32x4*)(ht + ((size_t)b * T_LEN + t) * 64 + w * 16 + hi * 4) = acc[nt];
    }
}

// ================= fused gated layer (MFMA) =================
// h is fp32 t-major: ht[b][t][64]. B-fragments built via cvt_pk on the fly.
template<int DO_SKIP>
__global__ __launch_bounds__(256) void layer_mfma(
    const float* __restrict__ htin, float* __restrict__ htout,
    u16* __restrict__ zTi, float* __restrict__ skipsum,
    const u16* __restrict__ w1p, const u16* __restrict__ swp, const u16* __restrict__ rwp,
    const float* __restrict__ fb, const float* __restrict__ gb,
    const float* __restrict__ sb, const float* __restrict__ rb,
    int d, int first, int last)
{
    __shared__ u16 zl[64 * 64];
    int tid = threadIdx.x;
    int w = tid >> 6, l = tid & 63;
    int lo = l & 15, hi = l >> 4;
    int nblk = T_LEN / 64;
    int b = blockIdx.x / nblk, t0 = (blockIdx.x % nblk) * 64;

    // ---- phase 1: GEMM1 (filt rows m=w*16.., gate rows m=64+w*16..) ----
    const uint4* w1v = (const uint4*)w1p;
    uint4 aF[4], aG[4];
#pragma unroll
    for (int kk = 0; kk < 4; ++kk) {
        aF[kk] = w1v[(w * 4 + kk) * 64 + l];
        aG[kk] = w1v[((w + 4) * 4 + kk) * 64 + l];
    }
    f32x4 accF[4], accG[4];
    {
        f32x4 iF, iG;
#pragma unroll
        for (int r = 0; r < 4; ++r) { iF[r] = fb[w * 16 + hi * 4 + r]; iG[r] = gb[w * 16 + hi * 4 + r]; }
#pragma unroll
        for (int nt = 0; nt < 4; ++nt) { accF[nt] = iF; accG[nt] = iG; }
    }
    const float* hb = htin + (size_t)b * T_LEN * 64;
#pragma unroll
    for (int nt = 0; nt < 4; ++nt) {
        int tc = t0 + nt * 16 + lo;
#pragma unroll
        for (int kk = 0; kk < 4; ++kk) {
            int tap = kk >> 1;                       // kk 0,1 -> t-d ; kk 2,3 -> t
            int c0 = (kk & 1) * 32 + hi * 8;
            int tt = tap ? tc : tc - d;
            int tcl = tt < 0 ? 0 : tt;
            const float* p = hb + (size_t)tcl * 64 + c0;
            f32x4 f0 = *(const f32x4*)p;
            f32x4 f1 = *(const f32x4*)(p + 4);
            if (tt < 0) {
#pragma unroll
                for (int r = 0; r < 4; ++r) { f0[r] = 0.f; f1[r] = 0.f; }
            }
            uint4 bv;
            bv.x = cvt2(f0[0], f0[1]); bv.y = cvt2(f0[2], f0[3]);
            bv.z = cvt2(f1[0], f1[1]); bv.w = cvt2(f1[2], f1[3]);
            accF[nt] = mfma16(aF[kk], bv, accF[nt]);
            accG[nt] = mfma16(aG[kk], bv, accG[nt]);
        }
    }

    // ---- activation + z staging ----
#pragma unroll
    for (int nt = 0; nt < 4; ++nt) {
        float zv[4];
#pragma unroll
        for (int r = 0; r < 4; ++r) {
            float f = accF[nt][r], g = accG[nt][r];
            float ef = __expf(2.f * f);
            float th = 1.f - 2.f * __builtin_amdgcn_rcpf(ef + 1.f);
            float sg = __builtin_amdgcn_rcpf(1.f + __expf(-g));
            zv[r] = th * sg;
        }
        int n = nt * 16 + lo;
        int k0 = w * 16 + hi * 4;
        int col = k0 ^ ((n & 7) << 3);
        unsigned p01 = cvt2(zv[0], zv[1]);
        unsigned p23 = cvt2(zv[2], zv[3]);
        *(unsigned*)(&zl[n * 64 + col]) = p01;
        *(unsigned*)(&zl[n * 64 + col + 2]) = p23;
        if (!DO_SKIP) {
            u16* zt = zTi + ((size_t)b * T_LEN + t0 + n) * 64 + k0;
            *(unsigned*)(zt) = p01;
            *(unsigned*)(zt + 2) = p23;
        }
    }
    __syncthreads();

    // ---- phase 2: res GEMM (+ skip GEMM for plan C) ----
    uint4 aS[4][2];
    f32x4 accS[4][4];
    if (DO_SKIP) {
        const uint4* swv = (const uint4*)swp;
#pragma unroll
        for (int mi = 0; mi < 4; ++mi) {
            aS[mi][0] = swv[((w * 4 + mi) * 2 + 0) * 64 + l];
            aS[mi][1] = swv[((w * 4 + mi) * 2 + 1) * 64 + l];
            f32x4 iS;
#pragma unroll
            for (int r = 0; r < 4; ++r) iS[r] = sb[(w * 4 + mi) * 16 + hi * 4 + r];
#pragma unroll
            for (int nt = 0; nt < 4; ++nt) accS[mi][nt] = iS;
        }
    }
    uint4 aR[2];
    f32x4 accR[4];
    if (!last) {
        const uint4* rwv = (const uint4*)rwp;
        aR[0] = rwv[(w * 2 + 0) * 64 + l];
        aR[1] = rwv[(w * 2 + 1) * 64 + l];
        f32x4 iR;
#pragma unroll
        for (int r = 0; r < 4; ++r) iR[r] = rb[w * 16 + hi * 4 + r];
#pragma unroll
        for (int nt = 0; nt < 4; ++nt) accR[nt] = iR;
    }
#pragma unroll
    for (int nt = 0; nt < 4; ++nt) {
        int n = nt * 16 + lo;
#pragma unroll
        for (int kk = 0; kk < 2; ++kk) {
            int kb = kk * 32 + hi * 8;
            uint4 bz = *(const uint4*)(&zl[n * 64 + (kb ^ ((n & 7) << 3))]);
            if (!last) accR[nt] = mfma16(aR[kk], bz, accR[nt]);
            if (DO_SKIP) {
#pragma unroll
                for (int mi = 0; mi < 4; ++mi)
                    accS[mi][nt] = mfma16(aS[mi][kk], bz, accS[mi][nt]);
            }
        }
    }

    // ---- epilogue: h_out = h_in + res (fp32 t-major) ----
    if (!last) {
#pragma unroll
        for (int nt = 0; nt < 4; ++nt) {
            int t = t0 + nt * 16 + lo;
            int o0 = w * 16 + hi * 4;
            f32x4 hv = *(const f32x4*)(hb + (size_t)t * 64 + o0);
#pragma unroll
            for (int r = 0; r < 4; ++r) hv[r] += accR[nt][r];
            *(f32x4*)(htout + ((size_t)b * T_LEN + t) * 64 + o0) = hv;
        }
    }
    if (DO_SKIP) {
#pragma unroll
        for (int mi = 0; mi < 4; ++mi) {
#pragma unroll
            for (int nt = 0; nt < 4; ++nt) {
                int t = t0 + nt * 16 + lo;
                int p0 = (w * 4 + mi) * 16 + hi * 4;
#pragma unroll
                for (int r = 0; r < 4; ++r) {
                    float* sp = &skipsum[((size_t)b * 256 + p0 + r) * T_LEN + t];
                    float v = accS[mi][nt][r];
                    if (first) *sp = v; else *sp = *sp + v;
                }
            }
        }
    }
}

// ================= post: skip-sum -> relu -> pp1 -> relu -> pp2 (MFMA) =================
template<int FROM_Z>
__global__ __launch_bounds__(256) void post_mfma(
    const u16* __restrict__ zT, const float* __restrict__ skipsum,
    const u16* __restrict__ swpAll, const float* __restrict__ sbsum,
    const u16* __restrict__ pp1p, const float* __restrict__ pp1b,
    const u16* __restrict__ pp2p, const float* __restrict__ pp2b,
    float* __restrict__ out)
{
    __shared__ u16 sl[64 * 256];
    int tid = threadIdx.x;
    int w = tid >> 6, l = tid & 63;
    int lo = l & 15, hi = l >> 4;
    int nblk = T_LEN / 64;
    int b = blockIdx.x / nblk, t0 = (blockIdx.x % nblk) * 64;

    // ---- stage s = relu(skip_sum) into sl ----
    if (FROM_Z) {
        f32x4 acc[4][4];
#pragma unroll
        for (int mi = 0; mi < 4; ++mi) {
            f32x4 iS;
#pragma unroll
            for (int r = 0; r < 4; ++r) iS[r] = sbsum[(w * 4 + mi) * 16 + hi * 4 + r];
#pragma unroll
            for (int nt = 0; nt < 4; ++nt) acc[mi][nt] = iS;
        }
        const uint4* swv = (const uint4*)swpAll;
        for (int i = 0; i < L_LAYERS; ++i) {
            const u16* zb = zT + ((size_t)i * 4 + b) * T_LEN * 64;
#pragma unroll
            for (int kk = 0; kk < 2; ++kk) {
                uint4 a[4];
#pragma unroll
                for (int mi = 0; mi < 4; ++mi)
                    a[mi] = swv[((i * 16 + w * 4 + mi) * 2 + kk) * 64 + l];
#pragma unroll
                for (int nt = 0; nt < 4; ++nt) {
                    uint4 bz = *(const uint4*)(zb + ((size_t)(t0 + nt * 16 + lo)) * 64 + kk * 32 + hi * 8);
#pragma unroll
                    for (int mi = 0; mi < 4; ++mi)
                        acc[mi][nt] = mfma16(a[mi], bz, acc[mi][nt]);
                }
            }
        }
#pragma unroll
        for (int mi = 0; mi < 4; ++mi) {
#pragma unroll
            for (int nt = 0; nt < 4; ++nt) {
                int n = nt * 16 + lo;
                int k0 = (w * 4 + mi) * 16 + hi * 4;
                int col = k0 ^ ((n & 15) << 3);
                float v0 = acc[mi][nt][0], v1 = acc[mi][nt][1], v2 = acc[mi][nt][2], v3 = acc[mi][nt][3];
                v0 = v0 > 0.f ? v0 : 0.f; v1 = v1 > 0.f ? v1 : 0.f;
                v2 = v2 > 0.f ? v2 : 0.f; v3 = v3 > 0.f ? v3 : 0.f;
                *(unsigned*)(&sl[n * 256 + col]) = cvt2(v0, v1);
                *(unsigned*)(&sl[n * 256 + col + 2]) = cvt2(v2, v3);
            }
        }
    } else {
#pragma unroll
        for (int mi = 0; mi < 4; ++mi) {
#pragma unroll
            for (int nt = 0; nt < 4; ++nt) {
                int n = nt * 16 + lo;
                int t = t0 + n;
                int p0 = (w * 4 + mi) * 16 + hi * 4;
                float v[4];
#pragma unroll
                for (int r = 0; r < 4; ++r) {
                    float s = skipsum[((size_t)b * 256 + p0 + r) * T_LEN + t];
                    v[r] = s > 0.f ? s : 0.f;
                }
                int col = p0 ^ ((n & 15) << 3);
                *(unsigned*)(&sl[n * 256 + col]) = cvt2(v[0], v[1]);
                *(unsigned*)(&sl[n * 256 + col + 2]) = cvt2(v[2], v[3]);
            }
        }
    }
    __syncthreads();

    // ---- pp1 ----
    f32x4 u[4][4];
#pragma unroll
    for (int mi = 0; mi < 4; ++mi) {
        f32x4 iU;
#pragma unroll
        for (int r = 0; r < 4; ++r) iU[r] = pp1b[(w * 4 + mi) * 16 + hi * 4 + r];
#pragma unroll
        for (int nt = 0; nt < 4; ++nt) u[mi][nt] = iU;
    }
    {
        const uint4* p1v = (const uint4*)pp1p;
#pragma unroll
        for (int kk = 0; kk < 8; ++kk) {
            uint4 a[4];
#pragma unroll
            for (int mi = 0; mi < 4; ++mi)
                a[mi] = p1v[((w * 4 + mi) * 8 + kk) * 64 + l];
#pragma unroll
            for (int nt = 0; nt < 4; ++nt) {
                int n = nt * 16 + lo;
                int kb = kk * 32 + hi * 8;
                uint4 bz = *(const uint4*)(&sl[n * 256 + (kb ^ ((n & 15) << 3))]);
#pragma unroll
                for (int mi = 0; mi < 4; ++mi)
                    u[mi][nt] = mfma16(a[mi], bz, u[mi][nt]);
            }
        }
    }
    __syncthreads();
#pragma unroll
    for (int mi = 0; mi < 4; ++mi) {
#pragma unroll
        for (int nt = 0; nt < 4; ++nt) {
            int n = nt * 16 + lo;
            int k0 = (w * 4 + mi) * 16 + hi * 4;
            int col = k0 ^ ((n & 15) << 3);
            float v0 = u[mi][nt][0], v1 = u[mi][nt][1], v2 = u[mi][nt][2], v3 = u[mi][nt][3];
            v0 = v0 > 0.f ? v0 : 0.f; v1 = v1 > 0.f ? v1 : 0.f;
            v2 = v2 > 0.f ? v2 : 0.f; v3 = v3 > 0.f ? v3 : 0.f;
            *(unsigned*)(&sl[n * 256 + col]) = cvt2(v0, v1);
            *(unsigned*)(&sl[n * 256 + col + 2]) = cvt2(v2, v3);
        }
    }
    __syncthreads();

    // ---- pp2 ----
    f32x4 vv[4][4];
#pragma unroll
    for (int mi = 0; mi < 4; ++mi) {
        f32x4 iV;
#pragma unroll
        for (int r = 0; r < 4; ++r) iV[r] = pp2b[(w * 4 + mi) * 16 + hi * 4 + r];
#pragma unroll
        for (int nt = 0; nt < 4; ++nt) vv[mi][nt] = iV;
    }
    {
        const uint4* p2v = (const uint4*)pp2p;
#pragma unroll
        for (int kk = 0; kk < 8; ++kk) {
            uint4 a[4];
#pragma unroll
            for (int mi = 0; mi < 4; ++mi)
                a[mi] = p2v[((w * 4 + mi) * 8 + kk) * 64 + l];
#pragma unroll
            for (int nt = 0; nt < 4; ++nt) {
                int n = nt * 16 + lo;
                int kb = kk * 32 + hi * 8;
                uint4 bz = *(const uint4*)(&sl[n * 256 + (kb ^ ((n & 15) << 3))]);
#pragma unroll
                for (int mi = 0; mi < 4; ++mi)
                    vv[mi][nt] = mfma16(a[mi], bz, vv[mi][nt]);
            }
        }
    }
#pragma unroll
    for (int mi = 0; mi < 4; ++mi) {
#pragma unroll
        for (int nt = 0; nt < 4; ++nt) {
            int t = t0 + nt * 16 + lo;
            int p0 = (w * 4 + mi) * 16 + hi * 4;
#pragma unroll
            for (int r = 0; r < 4; ++r)
                out[((size_t)b * 256 + p0 + r) * T_LEN + t] = vv[mi][nt][r];
        }
    }
}

// ================= launch =================
extern "C" void kernel_launch(void* const* d_in, const int* in_sizes, int n_in,
                              void* d_out, int out_size, void* d_ws, size_t ws_size,
                              hipStream_t stream)
{
    const float* x      = (const float*)d_in[0];
    const float* pre_w  = (const float*)d_in[1];
    const float* pre_b  = (const float*)d_in[2];
    const float* filt_w = (const float*)d_in[3];
    const float* filt_b = (const float*)d_in[4];
    const float* gate_w = (const float*)d_in[5];
    const float* gate_b = (const float*)d_in[6];
    const float* res_w  = (const float*)d_in[7];
    const float* res_b  = (const float*)d_in[8];
    const float* skip_w = (const float*)d_in[9];
    const float* skip_b = (const float*)d_in[10];
    const float* pp1_w  = (const float*)d_in[11];
    const float* pp1_b  = (const float*)d_in[12];
    const float* pp2_w  = (const float*)d_in[13];
    const float* pp2_b  = (const float*)d_in[14];
    float* outp = (float*)d_out;

    // d_out scratch: fp32 t-major h ping-pong (2 x 16.8 MB; post overwrites later)
    float* ht0 = outp;
    float* ht1 = outp + (size_t)4194304;

    const size_t ZT_BYTES   = (size_t)L_LAYERS * B_SZ * T_LEN * 64 * 2;  // 167,772,160
    const size_t SKIP_BYTES = (size_t)B_SZ * SKIP_C * T_LEN * 4;         // 67,108,864
    const bool planA = ws_size >= ZT_BYTES + (size_t)4 * 1024 * 1024;

    char* ws = (char*)d_ws;
    u16*   zT      = (u16*)ws;
    float* skipsum = (float*)ws;
    size_t packoff = planA ? ZT_BYTES : SKIP_BYTES;
    u16* w1p  = (u16*)(ws + packoff);
    u16* swp  = w1p + 327680;
    u16* rwp  = swp + 327680;
    u16* pp1p = rwp + 81920;
    u16* pp2p = pp1p + 65536;
    u16* prep = pp2p + 65536;
    float* sbsum = (float*)(prep + 16384);

    repack2<<<3457, 256, 0, stream>>>(filt_w, gate_w, skip_w, res_w, pp1_w, pp2_w, pre_w, skip_b,
                                      w1p, swp, rwp, pp1p, pp2p, prep, sbsum);

    pre_mfma<<<1024, 256, 0, stream>>>(x, prep, pre_b, ht0);

    const float* hi_ = ht0; float* ho_ = ht1;
    for (int i = 0; i < L_LAYERS; ++i) {
        int d = 1 << (i % 10);
        int first = (i == 0) ? 1 : 0;
        int last  = (i == L_LAYERS - 1) ? 1 : 0;
        if (planA)
            layer_mfma<0><<<1024, 256, 0, stream>>>(
                hi_, ho_,
                zT + (size_t)i * 4194304, skipsum,
                w1p + (size_t)i * 16384, swp + (size_t)i * 16384, rwp + (size_t)i * 4096,
                filt_b + i * 64, gate_b + i * 64, skip_b + i * 256, res_b + i * 64,
                d, first, last);
        else
            layer_mfma<1><<<1024, 256, 0, stream>>>(
                hi_, ho_,
                zT, skipsum,
                w1p + (size_t)i * 16384, swp + (size_t)i * 16384, rwp + (size_t)i * 4096,
                filt_b + i * 64, gate_b + i * 64, skip_b + i * 256, res_b + i * 64,
                d, first, last);
        { const float* tf = hi_; hi_ = ho_; ho_ = (float*)tf; }
    }

    if (planA)
        post_mfma<1><<<1024, 256, 0, stream>>>(zT, skipsum, swp, sbsum,
                                               pp1p, pp1_b, pp2p, pp2_b, outp);
    else
        post_mfma<0><<<1024, 256, 0, stream>>>(zT, skipsum, swp, sbsum,
                                               pp1p, pp1_b, pp2p, pp2_b, outp);
}

// Round 4
// 445.539 us; speedup vs baseline: 18.8593x; 1.3480x over previous
//
#include <hip/hip_runtime.h>

#define T_LEN   16384
#define B_SZ    4
#define AUDIO_C 256
#define RES_C   64
#define SKIP_C  256
#define L_LAYERS 20

typedef unsigned short u16;
using bf16x8 = __attribute__((ext_vector_type(8))) __bf16;
using f32x4  = __attribute__((ext_vector_type(4))) float;

__device__ __forceinline__ u16 f2bf(float x){
    union { float f; unsigned u; } v; v.f = x;
    return (u16)((v.u + 0x7FFFu + ((v.u >> 16) & 1u)) >> 16);
}
// compiler-fused v_cvt_pk_bf16_f32 (a -> low 16, b -> high 16)
__device__ __forceinline__ unsigned cvt2(float a, float b){
    union { __bf16 h[2]; unsigned u; } r;
    r.h[0] = (__bf16)a; r.h[1] = (__bf16)b;
    return r.u;
}
__device__ __forceinline__ f32x4 mfma16(uint4 a, uint4 b, f32x4 c){
    return __builtin_amdgcn_mfma_f32_16x16x32_bf16(
        __builtin_bit_cast(bf16x8, a), __builtin_bit_cast(bf16x8, b), c, 0, 0, 0);
}

// ================= repack: weights -> per-lane MFMA A-fragments (bf16) =================
__global__ __launch_bounds__(256) void repack2(
    const float* __restrict__ fw, const float* __restrict__ gw,
    const float* __restrict__ sw, const float* __restrict__ rw,
    const float* __restrict__ p1, const float* __restrict__ p2,
    const float* __restrict__ prw, const float* __restrict__ sb,
    u16* __restrict__ w1p, u16* __restrict__ swp, u16* __restrict__ rwp,
    u16* __restrict__ pp1p, u16* __restrict__ pp2p,
    u16* __restrict__ prep, float* __restrict__ sbsum)
{
    int idx = blockIdx.x * 256 + threadIdx.x;
    if (idx < 327680) {                             // w1p: GEMM1 A, K=128
        int j = idx & 7, l = (idx >> 3) & 63, kk = (idx >> 9) & 3, mt = (idx >> 11) & 7, i = idx >> 14;
        int m = mt * 16 + (l & 15);
        int k = kk * 32 + (l >> 4) * 8 + j;
        const float* srcw = (m < 64) ? fw : gw;
        int mm = m & 63, c = k & 63, tap = k >> 6;
        w1p[idx] = f2bf(srcw[((i * 64 + mm) * 64 + c) * 2 + tap]);
        return;
    }
    idx -= 327680;
    if (idx < 327680) {                             // swp: skip A, K=64
        int j = idx & 7, l = (idx >> 3) & 63, kk = (idx >> 9) & 1, mt = (idx >> 10) & 15, i = idx >> 14;
        int p = mt * 16 + (l & 15);
        int c = kk * 32 + (l >> 4) * 8 + j;
        swp[idx] = f2bf(sw[(i * 256 + p) * 64 + c]);
        return;
    }
    idx -= 327680;
    if (idx < 81920) {                              // rwp: res A, K=64
        int j = idx & 7, l = (idx >> 3) & 63, kk = (idx >> 9) & 1, mt = (idx >> 10) & 3, i = idx >> 12;
        int o = mt * 16 + (l & 15);
        int c = kk * 32 + (l >> 4) * 8 + j;
        rwp[idx] = f2bf(rw[(i * 64 + o) * 64 + c]);
        return;
    }
    idx -= 81920;
    if (idx < 65536) {                              // pp1p: K=256
        int j = idx & 7, l = (idx >> 3) & 63, kk = (idx >> 9) & 7, mt = idx >> 12;
        int m = mt * 16 + (l & 15);
        int k = kk * 32 + (l >> 4) * 8 + j;
        pp1p[idx] = f2bf(p1[m * 256 + k]);
        return;
    }
    idx -= 65536;
    if (idx < 65536) {                              // pp2p: K=256
        int j = idx & 7, l = (idx >> 3) & 63, kk = (idx >> 9) & 7, mt = idx >> 12;
        int m = mt * 16 + (l & 15);
        int k = kk * 32 + (l >> 4) * 8 + j;
        pp2p[idx] = f2bf(p2[m * 256 + k]);
        return;
    }
    idx -= 65536;
    if (idx < 16384) {                              // prep: pre A, M=64, K=256
        int j = idx & 7, l = (idx >> 3) & 63, kk = (idx >> 9) & 7, mt = idx >> 12;
        int m = mt * 16 + (l & 15);
        int k = kk * 32 + (l >> 4) * 8 + j;
        prep[idx] = f2bf(prw[m * 256 + k]);
        return;
    }
    idx -= 16384;
    if (idx < 256) {                                // sbsum[p] = sum_i skip_b[i][p]
        float s = 0.f;
        for (int i = 0; i < L_LAYERS; ++i) s += sb[i * 256 + idx];
        sbsum[idx] = s;
        return;
    }
}

// ================= pre (MFMA): ht[b][t][o] = pre_w @ x + pre_b ==================
__global__ __launch_bounds__(256) void pre_mfma(
    const float* __restrict__ x, const u16* __restrict__ prep,
    const float* __restrict__ pre_b, float* __restrict__ ht)
{
    __shared__ u16 sx[64 * 256];                    // 32 KB
    unsigned* sx32 = (unsigned*)sx;
    int tid = threadIdx.x;
    int w = tid >> 6, l = tid & 63;
    int lo = l & 15, hi = l >> 4;
    int nblk = T_LEN / 64;
    int b = blockIdx.x / nblk, t0 = (blockIdx.x % nblk) * 64;

    {
        int t = l;
        const float* xb = x + (size_t)b * AUDIO_C * T_LEN + t0 + t;
#pragma unroll 8
        for (int c2 = 0; c2 < 64; c2 += 2) {
            int c = w * 64 + c2;
            float v0 = xb[(size_t)c * T_LEN];
            float v1 = xb[(size_t)(c + 1) * T_LEN];
            int ch = c >> 3;
            int a32 = t * 128 + ((ch ^ (t & 7)) << 2) + ((c >> 1) & 3);
            sx32[a32] = cvt2(v0, v1);
        }
    }
    __syncthreads();

    const uint4* av = (const uint4*)prep;
    f32x4 acc[4];
    {
        f32x4 ib;
#pragma unroll
        for (int r = 0; r < 4; ++r) ib[r] = pre_b[w * 16 + hi * 4 + r];
#pragma unroll
        for (int nt = 0; nt < 4; ++nt) acc[nt] = ib;
    }
#pragma unroll
    for (int kk = 0; kk < 8; ++kk) {
        uint4 a = av[(w * 8 + kk) * 64 + l];
#pragma unroll
        for (int nt = 0; nt < 4; ++nt) {
            int t = nt * 16 + lo;
            int ch = kk * 4 + hi;
            uint4 bv = *(const uint4*)&sx32[t * 128 + ((ch ^ (t & 7)) << 2)];
            acc[nt] = mfma16(a, bv, acc[nt]);
        }
    }
#pragma unroll
    for (int nt = 0; nt < 4; ++nt) {
        int t = t0 + nt * 16 + lo;
        *(f32x4*)(ht + ((size_t)b * T_LEN + t) * 64 + w * 16 + hi * 4) = acc[nt];
    }
}

// ================= fused gated layer (MFMA, LDS-staged h taps) =================
template<int DO_SKIP>
__global__ __launch_bounds__(256) void layer_mfma(
    const float* __restrict__ htin, float* __restrict__ htout,
    u16* __restrict__ zTi, float* __restrict__ skipsum,
    const u16* __restrict__ w1p, const u16* __restrict__ swp, const u16* __restrict__ rwp,
    const float* __restrict__ fb, const float* __restrict__ gb,
    const float* __restrict__ sb, const float* __restrict__ rb,
    int d, int first, int last)
{
    __shared__ u16 hl[2 * 64 * 64];   // 16 KB: region0 = tap t-d, region1 = tap t
    __shared__ u16 zl[64 * 64];       // 8 KB
    int tid = threadIdx.x;
    int w = tid >> 6, l = tid & 63;
    int lo = l & 15, hi = l >> 4;
    int nblk = T_LEN / 64;
    int b = blockIdx.x / nblk, t0 = (blockIdx.x % nblk) * 64;
    const float* hb = htin + (size_t)b * T_LEN * 64;

    // ---- stage both taps -> bf16 LDS (swizzled granules, wide coalesced loads) ----
#pragma unroll
    for (int k = 0; k < 4; ++k) {
        int id = tid + k * 256;           // 0..1023 : 128 rows x 8 granules
        int row = id >> 3, g = id & 7;
        int rr = row & 63;
        int t = (row >> 6) ? (t0 + rr) : (t0 - d + rr);
        uint4 bv;
        if (t >= 0) {
            const float* p = hb + (size_t)t * 64 + g * 8;
            f32x4 f0 = *(const f32x4*)p;
            f32x4 f1 = *(const f32x4*)(p + 4);
            bv.x = cvt2(f0[0], f0[1]); bv.y = cvt2(f0[2], f0[3]);
            bv.z = cvt2(f1[0], f1[1]); bv.w = cvt2(f1[2], f1[3]);
        } else {
            bv = make_uint4(0u, 0u, 0u, 0u);
        }
        *(uint4*)(&hl[row * 64 + ((g ^ (row & 7)) << 3)]) = bv;
    }

    // ---- weight fragments (L2) issued while stage is in flight ----
    const uint4* w1v = (const uint4*)w1p;
    uint4 aF[4], aG[4];
#pragma unroll
    for (int kk = 0; kk < 4; ++kk) {
        aF[kk] = w1v[(w * 4 + kk) * 64 + l];
        aG[kk] = w1v[((w + 4) * 4 + kk) * 64 + l];
    }
    uint4 aR[2];
    if (!last) {
        const uint4* rwv = (const uint4*)rwp;
        aR[0] = rwv[(w * 2 + 0) * 64 + l];
        aR[1] = rwv[(w * 2 + 1) * 64 + l];
    }
    f32x4 accF[4], accG[4];
    {
        f32x4 iF, iG;
#pragma unroll
        for (int r = 0; r < 4; ++r) { iF[r] = fb[w * 16 + hi * 4 + r]; iG[r] = gb[w * 16 + hi * 4 + r]; }
#pragma unroll
        for (int nt = 0; nt < 4; ++nt) { accF[nt] = iF; accG[nt] = iG; }
    }
    __syncthreads();

    // ---- phase 1: GEMM1 from LDS ----
#pragma unroll
    for (int nt = 0; nt < 4; ++nt) {
        int n = nt * 16 + lo;
#pragma unroll
        for (int kk = 0; kk < 4; ++kk) {
            int gq = (kk & 1) * 4 + hi;
            uint4 bv = *(const uint4*)(&hl[(kk >> 1) * 4096 + n * 64 + ((gq ^ (n & 7)) << 3)]);
            accF[nt] = mfma16(aF[kk], bv, accF[nt]);
            accG[nt] = mfma16(aG[kk], bv, accG[nt]);
        }
    }

    // ---- activation + z staging ----
#pragma unroll
    for (int nt = 0; nt < 4; ++nt) {
        float zv[4];
#pragma unroll
        for (int r = 0; r < 4; ++r) {
            float f = accF[nt][r], g = accG[nt][r];
            float ef = __expf(2.f * f);
            float th = 1.f - 2.f * __builtin_amdgcn_rcpf(ef + 1.f);
            float sg = __builtin_amdgcn_rcpf(1.f + __expf(-g));
            zv[r] = th * sg;
        }
        int n = nt * 16 + lo;
        int k0 = w * 16 + hi * 4;
        int col = k0 ^ ((n & 7) << 3);
        unsigned p01 = cvt2(zv[0], zv[1]);
        unsigned p23 = cvt2(zv[2], zv[3]);
        *(unsigned*)(&zl[n * 64 + col]) = p01;
        *(unsigned*)(&zl[n * 64 + col + 2]) = p23;
        if (!DO_SKIP) {
            u16* zt = zTi + ((size_t)b * T_LEN + t0 + n) * 64 + k0;
            *(unsigned*)(zt) = p01;
            *(unsigned*)(zt + 2) = p23;
        }
    }
    __syncthreads();

    // ---- phase 2: res GEMM (+ skip GEMM for plan C) ----
    uint4 aS[4][2];
    f32x4 accS[4][4];
    if (DO_SKIP) {
        const uint4* swv = (const uint4*)swp;
#pragma unroll
        for (int mi = 0; mi < 4; ++mi) {
            aS[mi][0] = swv[((w * 4 + mi) * 2 + 0) * 64 + l];
            aS[mi][1] = swv[((w * 4 + mi) * 2 + 1) * 64 + l];
            f32x4 iS;
#pragma unroll
            for (int r = 0; r < 4; ++r) iS[r] = sb[(w * 4 + mi) * 16 + hi * 4 + r];
#pragma unroll
            for (int nt = 0; nt < 4; ++nt) accS[mi][nt] = iS;
        }
    }
    f32x4 accR[4];
    if (!last) {
        f32x4 iR;
#pragma unroll
        for (int r = 0; r < 4; ++r) iR[r] = rb[w * 16 + hi * 4 + r];
#pragma unroll
        for (int nt = 0; nt < 4; ++nt) accR[nt] = iR;
    }
#pragma unroll
    for (int nt = 0; nt < 4; ++nt) {
        int n = nt * 16 + lo;
#pragma unroll
        for (int kk = 0; kk < 2; ++kk) {
            int kb = kk * 32 + hi * 8;
            uint4 bz = *(const uint4*)(&zl[n * 64 + (kb ^ ((n & 7) << 3))]);
            if (!last) accR[nt] = mfma16(aR[kk], bz, accR[nt]);
            if (DO_SKIP) {
#pragma unroll
                for (int mi = 0; mi < 4; ++mi)
                    accS[mi][nt] = mfma16(aS[mi][kk], bz, accS[mi][nt]);
            }
        }
    }

    // ---- epilogue ----
    if (!last) {
#pragma unroll
        for (int nt = 0; nt < 4; ++nt) {
            int t = t0 + nt * 16 + lo;
            int o0 = w * 16 + hi * 4;
            f32x4 hv = *(const f32x4*)(hb + (size_t)t * 64 + o0);
#pragma unroll
            for (int r = 0; r < 4; ++r) hv[r] += accR[nt][r];
            *(f32x4*)(htout + ((size_t)b * T_LEN + t) * 64 + o0) = hv;
        }
    }
    if (DO_SKIP) {
#pragma unroll
        for (int mi = 0; mi < 4; ++mi) {
#pragma unroll
            for (int nt = 0; nt < 4; ++nt) {
                int t = t0 + nt * 16 + lo;
                int p0 = (w * 4 + mi) * 16 + hi * 4;
#pragma unroll
                for (int r = 0; r < 4; ++r) {
                    float* sp = &skipsum[((size_t)b * 256 + p0 + r) * T_LEN + t];
                    float v = accS[mi][nt][r];
                    if (first) *sp = v; else *sp = *sp + v;
                }
            }
        }
    }
}

// ================= plan B: skip reduce (z stream, 2-deep layer prefetch) ===========
// grid 2048 (t-tile 32). sOut[b][t][p] = relu(sum_i skip_i) bf16
__global__ __launch_bounds__(256) void skip_reduce(
    const u16* __restrict__ zT, const u16* __restrict__ swpAll,
    const float* __restrict__ sbsum, u16* __restrict__ sOut)
{
    int tid = threadIdx.x;
    int w = tid >> 6, l = tid & 63;
    int lo = l & 15, hi = l >> 4;
    int nblk = T_LEN / 32;
    int b = blockIdx.x / nblk, t0 = (blockIdx.x % nblk) * 32;

    f32x4 acc[4][2];
#pragma unroll
    for (int mi = 0; mi < 4; ++mi) {
        f32x4 iS;
#pragma unroll
        for (int r = 0; r < 4; ++r) iS[r] = sbsum[(w * 4 + mi) * 16 + hi * 4 + r];
        acc[mi][0] = iS; acc[mi][1] = iS;
    }

    size_t off0 = (size_t)(t0 + lo) * 64 + hi * 8;
    size_t off1 = (size_t)(t0 + 16 + lo) * 64 + hi * 8;
    const u16* zb0 = zT + (size_t)b * T_LEN * 64;
    uint4 c00 = *(const uint4*)(zb0 + off0);
    uint4 c10 = *(const uint4*)(zb0 + off0 + 32);
    uint4 c01 = *(const uint4*)(zb0 + off1);
    uint4 c11 = *(const uint4*)(zb0 + off1 + 32);

    const uint4* swv = (const uint4*)swpAll;
    for (int i = 0; i < L_LAYERS; ++i) {
        int in = (i < L_LAYERS - 1) ? i + 1 : i;
        const u16* zn = zT + ((size_t)in * 4 + b) * T_LEN * 64;
        uint4 n00 = *(const uint4*)(zn + off0);
        uint4 n10 = *(const uint4*)(zn + off0 + 32);
        uint4 n01 = *(const uint4*)(zn + off1);
        uint4 n11 = *(const uint4*)(zn + off1 + 32);

        uint4 a[4][2];
#pragma unroll
        for (int mi = 0; mi < 4; ++mi) {
            a[mi][0] = swv[((i * 16 + w * 4 + mi) * 2 + 0) * 64 + l];
            a[mi][1] = swv[((i * 16 + w * 4 + mi) * 2 + 1) * 64 + l];
        }
#pragma unroll
        for (int mi = 0; mi < 4; ++mi) {
            acc[mi][0] = mfma16(a[mi][0], c00, acc[mi][0]);
            acc[mi][0] = mfma16(a[mi][1], c10, acc[mi][0]);
            acc[mi][1] = mfma16(a[mi][0], c01, acc[mi][1]);
            acc[mi][1] = mfma16(a[mi][1], c11, acc[mi][1]);
        }
        c00 = n00; c10 = n10; c01 = n01; c11 = n11;
    }

#pragma unroll
    for (int mi = 0; mi < 4; ++mi) {
#pragma unroll
        for (int nt = 0; nt < 2; ++nt) {
            int t = t0 + nt * 16 + lo;
            int p0 = (w * 4 + mi) * 16 + hi * 4;
            float v0 = acc[mi][nt][0], v1 = acc[mi][nt][1];
            float v2 = acc[mi][nt][2], v3 = acc[mi][nt][3];
            v0 = v0 > 0.f ? v0 : 0.f; v1 = v1 > 0.f ? v1 : 0.f;
            v2 = v2 > 0.f ? v2 : 0.f; v3 = v3 > 0.f ? v3 : 0.f;
            u16* sp = sOut + ((size_t)b * T_LEN + t) * 256 + p0;
            *(unsigned*)(sp)     = cvt2(v0, v1);
            *(unsigned*)(sp + 2) = cvt2(v2, v3);
        }
    }
}

// ================= plan B: pp1 -> relu -> pp2 ===================================
__global__ __launch_bounds__(256) void post_pp(
    const u16* __restrict__ sIn,
    const u16* __restrict__ pp1p, const float* __restrict__ pp1b,
    const u16* __restrict__ pp2p, const float* __restrict__ pp2b,
    float* __restrict__ out)
{
    __shared__ u16 sl[64 * 256];     // 32 KB relu(u) staging
    int tid = threadIdx.x;
    int w = tid >> 6, l = tid & 63;
    int lo = l & 15, hi = l >> 4;
    int nblk = T_LEN / 64;
    int b = blockIdx.x / nblk, t0 = (blockIdx.x % nblk) * 64;

    f32x4 u[4][4];
#pragma unroll
    for (int mi = 0; mi < 4; ++mi) {
        f32x4 iU;
#pragma unroll
        for (int r = 0; r < 4; ++r) iU[r] = pp1b[(w * 4 + mi) * 16 + hi * 4 + r];
#pragma unroll
        for (int nt = 0; nt < 4; ++nt) u[mi][nt] = iU;
    }
    {
        const uint4* p1v = (const uint4*)pp1p;
        const u16* sb_ = sIn + (size_t)b * T_LEN * 256;
#pragma unroll
        for (int kk = 0; kk < 8; ++kk) {
            uint4 a[4];
#pragma unroll
            for (int mi = 0; mi < 4; ++mi)
                a[mi] = p1v[((w * 4 + mi) * 8 + kk) * 64 + l];
#pragma unroll
            for (int nt = 0; nt < 4; ++nt) {
                uint4 bz = *(const uint4*)(sb_ + (size_t)(t0 + nt * 16 + lo) * 256 + kk * 32 + hi * 8);
#pragma unroll
                for (int mi = 0; mi < 4; ++mi)
                    u[mi][nt] = mfma16(a[mi], bz, u[mi][nt]);
            }
        }
    }
#pragma unroll
    for (int mi = 0; mi < 4; ++mi) {
#pragma unroll
        for (int nt = 0; nt < 4; ++nt) {
            int n = nt * 16 + lo;
            int k0 = (w * 4 + mi) * 16 + hi * 4;
            int col = k0 ^ ((n & 15) << 3);
            float v0 = u[mi][nt][0], v1 = u[mi][nt][1], v2 = u[mi][nt][2], v3 = u[mi][nt][3];
            v0 = v0 > 0.f ? v0 : 0.f; v1 = v1 > 0.f ? v1 : 0.f;
            v2 = v2 > 0.f ? v2 : 0.f; v3 = v3 > 0.f ? v3 : 0.f;
            *(unsigned*)(&sl[n * 256 + col]) = cvt2(v0, v1);
            *(unsigned*)(&sl[n * 256 + col + 2]) = cvt2(v2, v3);
        }
    }
    __syncthreads();

    f32x4 vv[4][4];
#pragma unroll
    for (int mi = 0; mi < 4; ++mi) {
        f32x4 iV;
#pragma unroll
        for (int r = 0; r < 4; ++r) iV[r] = pp2b[(w * 4 + mi) * 16 + hi * 4 + r];
#pragma unroll
        for (int nt = 0; nt < 4; ++nt) vv[mi][nt] = iV;
    }
    {
        const uint4* p2v = (const uint4*)pp2p;
#pragma unroll
        for (int kk = 0; kk < 8; ++kk) {
            uint4 a[4];
#pragma unroll
            for (int mi = 0; mi < 4; ++mi)
                a[mi] = p2v[((w * 4 + mi) * 8 + kk) * 64 + l];
#pragma unroll
            for (int nt = 0; nt < 4; ++nt) {
                int n = nt * 16 + lo;
                int kb = kk * 32 + hi * 8;
                uint4 bz = *(const uint4*)(&sl[n * 256 + (kb ^ ((n & 15) << 3))]);
#pragma unroll
                for (int mi = 0; mi < 4; ++mi)
                    vv[mi][nt] = mfma16(a[mi], bz, vv[mi][nt]);
            }
        }
    }
#pragma unroll
    for (int mi = 0; mi < 4; ++mi) {
#pragma unroll
        for (int nt = 0; nt < 4; ++nt) {
            int t = t0 + nt * 16 + lo;
            int p0 = (w * 4 + mi) * 16 + hi * 4;
#pragma unroll
            for (int r = 0; r < 4; ++r)
                out[((size_t)b * 256 + p0 + r) * T_LEN + t] = vv[mi][nt][r];
        }
    }
}

// ================= plan A/C post (round-3, proven) =================
template<int FROM_Z>
__global__ __launch_bounds__(256) void post_mfma(
    const u16* __restrict__ zT, const float* __restrict__ skipsum,
    const u16* __restrict__ swpAll, const float* __restrict__ sbsum,
    const u16* __restrict__ pp1p, const float* __restrict__ pp1b,
    const u16* __restrict__ pp2p, const float* __restrict__ pp2b,
    float* __restrict__ out)
{
    __shared__ u16 sl[64 * 256];
    int tid = threadIdx.x;
    int w = tid >> 6, l = tid & 63;
    int lo = l & 15, hi = l >> 4;
    int nblk = T_LEN / 64;
    int b = blockIdx.x / nblk, t0 = (blockIdx.x % nblk) * 64;

    if (FROM_Z) {
        f32x4 acc[4][4];
#pragma unroll
        for (int mi = 0; mi < 4; ++mi) {
            f32x4 iS;
#pragma unroll
            for (int r = 0; r < 4; ++r) iS[r] = sbsum[(w * 4 + mi) * 16 + hi * 4 + r];
#pragma unroll
            for (int nt = 0; nt < 4; ++nt) acc[mi][nt] = iS;
        }
        const uint4* swv = (const uint4*)swpAll;
        for (int i = 0; i < L_LAYERS; ++i) {
            const u16* zb = zT + ((size_t)i * 4 + b) * T_LEN * 64;
#pragma unroll
            for (int kk = 0; kk < 2; ++kk) {
                uint4 a[4];
#pragma unroll
                for (int mi = 0; mi < 4; ++mi)
                    a[mi] = swv[((i * 16 + w * 4 + mi) * 2 + kk) * 64 + l];
#pragma unroll
                for (int nt = 0; nt < 4; ++nt) {
                    uint4 bz = *(const uint4*)(zb + ((size_t)(t0 + nt * 16 + lo)) * 64 + kk * 32 + hi * 8);
#pragma unroll
                    for (int mi = 0; mi < 4; ++mi)
                        acc[mi][nt] = mfma16(a[mi], bz, acc[mi][nt]);
                }
            }
        }
#pragma unroll
        for (int mi = 0; mi < 4; ++mi) {
#pragma unroll
            for (int nt = 0; nt < 4; ++nt) {
                int n = nt * 16 + lo;
                int k0 = (w * 4 + mi) * 16 + hi * 4;
                int col = k0 ^ ((n & 15) << 3);
                float v0 = acc[mi][nt][0], v1 = acc[mi][nt][1], v2 = acc[mi][nt][2], v3 = acc[mi][nt][3];
                v0 = v0 > 0.f ? v0 : 0.f; v1 = v1 > 0.f ? v1 : 0.f;
                v2 = v2 > 0.f ? v2 : 0.f; v3 = v3 > 0.f ? v3 : 0.f;
                *(unsigned*)(&sl[n * 256 + col]) = cvt2(v0, v1);
                *(unsigned*)(&sl[n * 256 + col + 2]) = cvt2(v2, v3);
            }
        }
    } else {
#pragma unroll
        for (int mi = 0; mi < 4; ++mi) {
#pragma unroll
            for (int nt = 0; nt < 4; ++nt) {
                int n = nt * 16 + lo;
                int t = t0 + n;
                int p0 = (w * 4 + mi) * 16 + hi * 4;
                float v[4];
#pragma unroll
                for (int r = 0; r < 4; ++r) {
                    float s = skipsum[((size_t)b * 256 + p0 + r) * T_LEN + t];
                    v[r] = s > 0.f ? s : 0.f;
                }
                int col = p0 ^ ((n & 15) << 3);
                *(unsigned*)(&sl[n * 256 + col]) = cvt2(v[0], v[1]);
                *(unsigned*)(&sl[n * 256 + col + 2]) = cvt2(v[2], v[3]);
            }
        }
    }
    __syncthreads();

    f32x4 u[4][4];
#pragma unroll
    for (int mi = 0; mi < 4; ++mi) {
        f32x4 iU;
#pragma unroll
        for (int r = 0; r < 4; ++r) iU[r] = pp1b[(w * 4 + mi) * 16 + hi * 4 + r];
#pragma unroll
        for (int nt = 0; nt < 4; ++nt) u[mi][nt] = iU;
    }
    {
        const uint4* p1v = (const uint4*)pp1p;
#pragma unroll
        for (int kk = 0; kk < 8; ++kk) {
            uint4 a[4];
#pragma unroll
            for (int mi = 0; mi < 4; ++mi)
                a[mi] = p1v[((w * 4 + mi) * 8 + kk) * 64 + l];
#pragma unroll
            for (int nt = 0; nt < 4; ++nt) {
                int n = nt * 16 + lo;
                int kb = kk * 32 + hi * 8;
                uint4 bz = *(const uint4*)(&sl[n * 256 + (kb ^ ((n & 15) << 3))]);
#pragma unroll
                for (int mi = 0; mi < 4; ++mi)
                    u[mi][nt] = mfma16(a[mi], bz, u[mi][nt]);
            }
        }
    }
    __syncthreads();
#pragma unroll
    for (int mi = 0; mi < 4; ++mi) {
#pragma unroll
        for (int nt = 0; nt < 4; ++nt) {
            int n = nt * 16 + lo;
            int k0 = (w * 4 + mi) * 16 + hi * 4;
            int col = k0 ^ ((n & 15) << 3);
            float v0 = u[mi][nt][0], v1 = u[mi][nt][1], v2 = u[mi][nt][2], v3 = u[mi][nt][3];
            v0 = v0 > 0.f ? v0 : 0.f; v1 = v1 > 0.f ? v1 : 0.f;
            v2 = v2 > 0.f ? v2 : 0.f; v3 = v3 > 0.f ? v3 : 0.f;
            *(unsigned*)(&sl[n * 256 + col]) = cvt2(v0, v1);
            *(unsigned*)(&sl[n * 256 + col + 2]) = cvt2(v2, v3);
        }
    }
    __syncthreads();

    f32x4 vv[4][4];
#pragma unroll
    for (int mi = 0; mi < 4; ++mi) {
        f32x4 iV;
#pragma unroll
        for (int r = 0; r < 4; ++r) iV[r] = pp2b[(w * 4 + mi) * 16 + hi * 4 + r];
#pragma unroll
        for (int nt = 0; nt < 4; ++nt) vv[mi][nt] = iV;
    }
    {
        const uint4* p2v = (const uint4*)pp2p;
#pragma unroll
        for (int kk = 0; kk < 8; ++kk) {
            uint4 a[4];
#pragma unroll
            for (int mi = 0; mi < 4; ++mi)
                a[mi] = p2v[((w * 4 + mi) * 8 + kk) * 64 + l];
#pragma unroll
            for (int nt = 0; nt < 4; ++nt) {
                int n = nt * 16 + lo;
                int kb = kk * 32 + hi * 8;
                uint4 bz = *(const uint4*)(&sl[n * 256 + (kb ^ ((n & 15) << 3))]);
#pragma unroll
                for (int mi = 0; mi < 4; ++mi)
                    vv[mi][nt] = mfma16(a[mi], bz, vv[mi][nt]);
            }
        }
    }
#pragma unroll
    for (int mi = 0; mi < 4; ++mi) {
#pragma unroll
        for (int nt = 0; nt < 4; ++nt) {
            int t = t0 + nt * 16 + lo;
            int p0 = (w * 4 + mi) * 16 + hi * 4;
#pragma unroll
            for (int r = 0; r < 4; ++r)
                out[((size_t)b * 256 + p0 + r) * T_LEN + t] = vv[mi][nt][r];
        }
    }
}

// ================= launch =================
extern "C" void kernel_launch(void* const* d_in, const int* in_sizes, int n_in,
                              void* d_out, int out_size, void* d_ws, size_t ws_size,
                              hipStream_t stream)
{
    const float* x      = (const float*)d_in[0];
    const float* pre_w  = (const float*)d_in[1];
    const float* pre_b  = (const float*)d_in[2];
    const float* filt_w = (const float*)d_in[3];
    const float* filt_b = (const float*)d_in[4];
    const float* gate_w = (const float*)d_in[5];
    const float* gate_b = (const float*)d_in[6];
    const float* res_w  = (const float*)d_in[7];
    const float* res_b  = (const float*)d_in[8];
    const float* skip_w = (const float*)d_in[9];
    const float* skip_b = (const float*)d_in[10];
    const float* pp1_w  = (const float*)d_in[11];
    const float* pp1_b  = (const float*)d_in[12];
    const float* pp2_w  = (const float*)d_in[13];
    const float* pp2_b  = (const float*)d_in[14];
    float* outp = (float*)d_out;

    float* ht0 = outp;
    float* ht1 = outp + (size_t)4194304;

    const size_t ZT_BYTES   = (size_t)L_LAYERS * B_SZ * T_LEN * 64 * 2;   // 167,772,160
    const size_t SKIP_BYTES = (size_t)B_SZ * SKIP_C * T_LEN * 4;          // 67,108,864
    const size_t PACK_PAD   = (size_t)2 * 1024 * 1024;
    const size_t S_BYTES    = (size_t)B_SZ * T_LEN * SKIP_C * 2;          // 33,554,432

    const bool planB = ws_size >= ZT_BYTES + PACK_PAD + S_BYTES;
    const bool planA = !planB && ws_size >= ZT_BYTES + (size_t)4 * 1024 * 1024;
    const bool useZ  = planA || planB;

    char* ws = (char*)d_ws;
    u16*   zT      = (u16*)ws;
    float* skipsum = (float*)ws;
    size_t packoff = useZ ? ZT_BYTES : SKIP_BYTES;
    u16* w1p  = (u16*)(ws + packoff);
    u16* swp  = w1p + 327680;
    u16* rwp  = swp + 327680;
    u16* pp1p = rwp + 81920;
    u16* pp2p = pp1p + 65536;
    u16* prep = pp2p + 65536;
    float* sbsum = (float*)(prep + 16384);
    u16* sOut = (u16*)(ws + ZT_BYTES + PACK_PAD);

    repack2<<<3457, 256, 0, stream>>>(filt_w, gate_w, skip_w, res_w, pp1_w, pp2_w, pre_w, skip_b,
                                      w1p, swp, rwp, pp1p, pp2p, prep, sbsum);

    pre_mfma<<<1024, 256, 0, stream>>>(x, prep, pre_b, ht0);

    const float* hi_ = ht0; float* ho_ = ht1;
    for (int i = 0; i < L_LAYERS; ++i) {
        int d = 1 << (i % 10);
        int first = (i == 0) ? 1 : 0;
        int last  = (i == L_LAYERS - 1) ? 1 : 0;
        if (useZ)
            layer_mfma<0><<<1024, 256, 0, stream>>>(
                hi_, ho_,
                zT + (size_t)i * 4194304, skipsum,
                w1p + (size_t)i * 16384, swp + (size_t)i * 16384, rwp + (size_t)i * 4096,
                filt_b + i * 64, gate_b + i * 64, skip_b + i * 256, res_b + i * 64,
                d, first, last);
        else
            layer_mfma<1><<<1024, 256, 0, stream>>>(
                hi_, ho_,
                zT, skipsum,
                w1p + (size_t)i * 16384, swp + (size_t)i * 16384, rwp + (size_t)i * 4096,
                filt_b + i * 64, gate_b + i * 64, skip_b + i * 256, res_b + i * 64,
                d, first, last);
        { const float* tf = hi_; hi_ = ho_; ho_ = (float*)tf; }
    }

    if (planB) {
        skip_reduce<<<2048, 256, 0, stream>>>(zT, swp, sbsum, sOut);
        post_pp<<<1024, 256, 0, stream>>>(sOut, pp1p, pp1_b, pp2p, pp2_b, outp);
    } else if (planA) {
        post_mfma<1><<<1024, 256, 0, stream>>>(zT, skipsum, swp, sbsum,
                                               pp1p, pp1_b, pp2p, pp2_b, outp);
    } else {
        post_mfma<0><<<1024, 256, 0, stream>>>(zT, skipsum, swp, sbsum,
                                               pp1p, pp1_b, pp2p, pp2_b, outp);
    }
}

// Round 5
// 350.869 us; speedup vs baseline: 23.9478x; 1.2698x over previous
//
#include <hip/hip_runtime.h>

#define T_LEN   16384
#define B_SZ    4
#define AUDIO_C 256
#define RES_C   64
#define SKIP_C  256
#define L_LAYERS 20

typedef unsigned short u16;
using bf16x8 = __attribute__((ext_vector_type(8))) __bf16;
using f32x4  = __attribute__((ext_vector_type(4))) float;

__device__ __forceinline__ u16 f2bf(float x){
    union { float f; unsigned u; } v; v.f = x;
    return (u16)((v.u + 0x7FFFu + ((v.u >> 16) & 1u)) >> 16);
}
// compiler-fused v_cvt_pk_bf16_f32 (a -> low 16, b -> high 16)
__device__ __forceinline__ unsigned cvt2(float a, float b){
    union { __bf16 h[2]; unsigned u; } r;
    r.h[0] = (__bf16)a; r.h[1] = (__bf16)b;
    return r.u;
}
__device__ __forceinline__ f32x4 mfma16(uint4 a, uint4 b, f32x4 c){
    return __builtin_amdgcn_mfma_f32_16x16x32_bf16(
        __builtin_bit_cast(bf16x8, a), __builtin_bit_cast(bf16x8, b), c, 0, 0, 0);
}
// XCD-aware bijective swizzle for grid=1024 (8 XCDs x 128 chunk)
__device__ __forceinline__ int xcd_swz(int bid){
    return (bid & 7) * 128 + (bid >> 3);
}

// ================= repack: weights -> per-lane MFMA A-fragments (bf16) =================
__global__ __launch_bounds__(256) void repack2(
    const float* __restrict__ fw, const float* __restrict__ gw,
    const float* __restrict__ sw, const float* __restrict__ rw,
    const float* __restrict__ p1, const float* __restrict__ p2,
    const float* __restrict__ prw, const float* __restrict__ sb,
    u16* __restrict__ w1p, u16* __restrict__ swp, u16* __restrict__ rwp,
    u16* __restrict__ pp1p, u16* __restrict__ pp2p,
    u16* __restrict__ prep, float* __restrict__ sbsum)
{
    int idx = blockIdx.x * 256 + threadIdx.x;
    if (idx < 327680) {                             // w1p: GEMM1 A, K=128
        int j = idx & 7, l = (idx >> 3) & 63, kk = (idx >> 9) & 3, mt = (idx >> 11) & 7, i = idx >> 14;
        int m = mt * 16 + (l & 15);
        int k = kk * 32 + (l >> 4) * 8 + j;
        const float* srcw = (m < 64) ? fw : gw;
        int mm = m & 63, c = k & 63, tap = k >> 6;
        w1p[idx] = f2bf(srcw[((i * 64 + mm) * 64 + c) * 2 + tap]);
        return;
    }
    idx -= 327680;
    if (idx < 327680) {                             // swp: skip A, K=64
        int j = idx & 7, l = (idx >> 3) & 63, kk = (idx >> 9) & 1, mt = (idx >> 10) & 15, i = idx >> 14;
        int p = mt * 16 + (l & 15);
        int c = kk * 32 + (l >> 4) * 8 + j;
        swp[idx] = f2bf(sw[(i * 256 + p) * 64 + c]);
        return;
    }
    idx -= 327680;
    if (idx < 81920) {                              // rwp: res A, K=64
        int j = idx & 7, l = (idx >> 3) & 63, kk = (idx >> 9) & 1, mt = (idx >> 10) & 3, i = idx >> 12;
        int o = mt * 16 + (l & 15);
        int c = kk * 32 + (l >> 4) * 8 + j;
        rwp[idx] = f2bf(rw[(i * 64 + o) * 64 + c]);
        return;
    }
    idx -= 81920;
    if (idx < 65536) {                              // pp1p: K=256
        int j = idx & 7, l = (idx >> 3) & 63, kk = (idx >> 9) & 7, mt = idx >> 12;
        int m = mt * 16 + (l & 15);
        int k = kk * 32 + (l >> 4) * 8 + j;
        pp1p[idx] = f2bf(p1[m * 256 + k]);
        return;
    }
    idx -= 65536;
    if (idx < 65536) {                              // pp2p: K=256
        int j = idx & 7, l = (idx >> 3) & 63, kk = (idx >> 9) & 7, mt = idx >> 12;
        int m = mt * 16 + (l & 15);
        int k = kk * 32 + (l >> 4) * 8 + j;
        pp2p[idx] = f2bf(p2[m * 256 + k]);
        return;
    }
    idx -= 65536;
    if (idx < 16384) {                              // prep: pre A, M=64, K=256
        int j = idx & 7, l = (idx >> 3) & 63, kk = (idx >> 9) & 7, mt = idx >> 12;
        int m = mt * 16 + (l & 15);
        int k = kk * 32 + (l >> 4) * 8 + j;
        prep[idx] = f2bf(prw[m * 256 + k]);
        return;
    }
    idx -= 16384;
    if (idx < 256) {                                // sbsum[p] = sum_i skip_b[i][p]
        float s = 0.f;
        for (int i = 0; i < L_LAYERS; ++i) s += sb[i * 256 + idx];
        sbsum[idx] = s;
        return;
    }
}

// ================= pre (MFMA): ht[b][t][o] = pre_w @ x + pre_b ==================
__global__ __launch_bounds__(256) void pre_mfma(
    const float* __restrict__ x, const u16* __restrict__ prep,
    const float* __restrict__ pre_b, float* __restrict__ ht)
{
    __shared__ u16 sx[64 * 256];                    // 32 KB
    unsigned* sx32 = (unsigned*)sx;
    int tid = threadIdx.x;
    int w = tid >> 6, l = tid & 63;
    int lo = l & 15, hi = l >> 4;
    int wg = xcd_swz(blockIdx.x);
    int b = wg >> 8, t0 = (wg & 255) * 64;

    {
        int t = l;
        const float* xb = x + (size_t)b * AUDIO_C * T_LEN + t0 + t;
#pragma unroll 8
        for (int c2 = 0; c2 < 64; c2 += 2) {
            int c = w * 64 + c2;
            float v0 = xb[(size_t)c * T_LEN];
            float v1 = xb[(size_t)(c + 1) * T_LEN];
            int ch = c >> 3;
            int a32 = t * 128 + ((ch ^ (t & 7)) << 2) + ((c >> 1) & 3);
            sx32[a32] = cvt2(v0, v1);
        }
    }
    __syncthreads();

    const uint4* av = (const uint4*)prep;
    f32x4 acc[4];
    {
        f32x4 ib;
#pragma unroll
        for (int r = 0; r < 4; ++r) ib[r] = pre_b[w * 16 + hi * 4 + r];
#pragma unroll
        for (int nt = 0; nt < 4; ++nt) acc[nt] = ib;
    }
#pragma unroll
    for (int kk = 0; kk < 8; ++kk) {
        uint4 a = av[(w * 8 + kk) * 64 + l];
#pragma unroll
        for (int nt = 0; nt < 4; ++nt) {
            int t = nt * 16 + lo;
            int ch = kk * 4 + hi;
            uint4 bv = *(const uint4*)&sx32[t * 128 + ((ch ^ (t & 7)) << 2)];
            acc[nt] = mfma16(a, bv, acc[nt]);
        }
    }
#pragma unroll
    for (int nt = 0; nt < 4; ++nt) {
        int t = t0 + nt * 16 + lo;
        *(f32x4*)(ht + ((size_t)b * T_LEN + t) * 64 + w * 16 + hi * 4) = acc[nt];
    }
}

// ================= fused gated layer (MFMA, LDS-staged h taps) =================
template<int DO_SKIP>
__global__ __launch_bounds__(256) void layer_mfma(
    const float* __restrict__ htin, float* __restrict__ htout,
    u16* __restrict__ zTi, float* __restrict__ skipsum,
    const u16* __restrict__ w1p, const u16* __restrict__ swp, const u16* __restrict__ rwp,
    const float* __restrict__ fb, const float* __restrict__ gb,
    const float* __restrict__ sb, const float* __restrict__ rb,
    int d, int first, int last)
{
    __shared__ u16 hl[2 * 64 * 64];   // 16 KB: region0 = tap t-d, region1 = tap t
    __shared__ u16 zl[64 * 64];       // 8 KB
    int tid = threadIdx.x;
    int w = tid >> 6, l = tid & 63;
    int lo = l & 15, hi = l >> 4;
    int wg = xcd_swz(blockIdx.x);
    int b = wg >> 8, t0 = (wg & 255) * 64;
    const float* hb = htin + (size_t)b * T_LEN * 64;

    // ---- stage both taps -> bf16 LDS (swizzled granules, wide coalesced loads) ----
#pragma unroll
    for (int k = 0; k < 4; ++k) {
        int id = tid + k * 256;           // 0..1023 : 128 rows x 8 granules
        int row = id >> 3, g = id & 7;
        int rr = row & 63;
        int t = (row >> 6) ? (t0 + rr) : (t0 - d + rr);
        uint4 bv;
        if (t >= 0) {
            const float* p = hb + (size_t)t * 64 + g * 8;
            f32x4 f0 = *(const f32x4*)p;
            f32x4 f1 = *(const f32x4*)(p + 4);
            bv.x = cvt2(f0[0], f0[1]); bv.y = cvt2(f0[2], f0[3]);
            bv.z = cvt2(f1[0], f1[1]); bv.w = cvt2(f1[2], f1[3]);
        } else {
            bv = make_uint4(0u, 0u, 0u, 0u);
        }
        *(uint4*)(&hl[row * 64 + ((g ^ (row & 7)) << 3)]) = bv;
    }

    // ---- weight fragments (L2) issued while stage is in flight ----
    const uint4* w1v = (const uint4*)w1p;
    uint4 aF[4], aG[4];
#pragma unroll
    for (int kk = 0; kk < 4; ++kk) {
        aF[kk] = w1v[(w * 4 + kk) * 64 + l];
        aG[kk] = w1v[((w + 4) * 4 + kk) * 64 + l];
    }
    uint4 aR[2];
    if (!last) {
        const uint4* rwv = (const uint4*)rwp;
        aR[0] = rwv[(w * 2 + 0) * 64 + l];
        aR[1] = rwv[(w * 2 + 1) * 64 + l];
    }
    f32x4 accF[4], accG[4];
    {
        f32x4 iF, iG;
#pragma unroll
        for (int r = 0; r < 4; ++r) { iF[r] = fb[w * 16 + hi * 4 + r]; iG[r] = gb[w * 16 + hi * 4 + r]; }
#pragma unroll
        for (int nt = 0; nt < 4; ++nt) { accF[nt] = iF; accG[nt] = iG; }
    }
    __syncthreads();

    // ---- phase 1: GEMM1 from LDS ----
#pragma unroll
    for (int nt = 0; nt < 4; ++nt) {
        int n = nt * 16 + lo;
#pragma unroll
        for (int kk = 0; kk < 4; ++kk) {
            int gq = (kk & 1) * 4 + hi;
            uint4 bv = *(const uint4*)(&hl[(kk >> 1) * 4096 + n * 64 + ((gq ^ (n & 7)) << 3)]);
            accF[nt] = mfma16(aF[kk], bv, accF[nt]);
            accG[nt] = mfma16(aG[kk], bv, accG[nt]);
        }
    }

    // ---- activation + z staging (LDS only; bulk global write after barrier) ----
#pragma unroll
    for (int nt = 0; nt < 4; ++nt) {
        float zv[4];
#pragma unroll
        for (int r = 0; r < 4; ++r) {
            float f = accF[nt][r], g = accG[nt][r];
            float ef = __expf(2.f * f);
            float th = 1.f - 2.f * __builtin_amdgcn_rcpf(ef + 1.f);
            float sg = __builtin_amdgcn_rcpf(1.f + __expf(-g));
            zv[r] = th * sg;
        }
        int n = nt * 16 + lo;
        int k0 = w * 16 + hi * 4;
        int col = k0 ^ ((n & 7) << 3);
        *(unsigned*)(&zl[n * 64 + col]) = cvt2(zv[0], zv[1]);
        *(unsigned*)(&zl[n * 64 + col + 2]) = cvt2(zv[2], zv[3]);
    }
    __syncthreads();

    // ---- bulk coalesced z write (plan A/B): 128B rows from zl ----
    if (!DO_SKIP) {
#pragma unroll
        for (int q = 0; q < 2; ++q) {
            int idx = tid + q * 256;          // 512 chunks of 16B
            int row = idx >> 3, s = idx & 7;
            uint4 v = *(const uint4*)(&zl[row * 64 + ((s ^ (row & 7)) << 3)]);
            *(uint4*)(zTi + ((size_t)b * T_LEN + t0 + row) * 64 + s * 8) = v;
        }
    }

    // ---- phase 2: res GEMM (+ skip GEMM for plan C) ----
    uint4 aS[4][2];
    f32x4 accS[4][4];
    if (DO_SKIP) {
        const uint4* swv = (const uint4*)swp;
#pragma unroll
        for (int mi = 0; mi < 4; ++mi) {
            aS[mi][0] = swv[((w * 4 + mi) * 2 + 0) * 64 + l];
            aS[mi][1] = swv[((w * 4 + mi) * 2 + 1) * 64 + l];
            f32x4 iS;
#pragma unroll
            for (int r = 0; r < 4; ++r) iS[r] = sb[(w * 4 + mi) * 16 + hi * 4 + r];
#pragma unroll
            for (int nt = 0; nt < 4; ++nt) accS[mi][nt] = iS;
        }
    }
    f32x4 accR[4];
    if (!last) {
        f32x4 iR;
#pragma unroll
        for (int r = 0; r < 4; ++r) iR[r] = rb[w * 16 + hi * 4 + r];
#pragma unroll
        for (int nt = 0; nt < 4; ++nt) accR[nt] = iR;
    }
#pragma unroll
    for (int nt = 0; nt < 4; ++nt) {
        int n = nt * 16 + lo;
#pragma unroll
        for (int kk = 0; kk < 2; ++kk) {
            int kb = kk * 32 + hi * 8;
            uint4 bz = *(const uint4*)(&zl[n * 64 + (kb ^ ((n & 7) << 3))]);
            if (!last) accR[nt] = mfma16(aR[kk], bz, accR[nt]);
            if (DO_SKIP) {
#pragma unroll
                for (int mi = 0; mi < 4; ++mi)
                    accS[mi][nt] = mfma16(aS[mi][kk], bz, accS[mi][nt]);
            }
        }
    }

    // ---- epilogue ----
    if (!last) {
#pragma unroll
        for (int nt = 0; nt < 4; ++nt) {
            int t = t0 + nt * 16 + lo;
            int o0 = w * 16 + hi * 4;
            f32x4 hv = *(const f32x4*)(hb + (size_t)t * 64 + o0);
#pragma unroll
            for (int r = 0; r < 4; ++r) hv[r] += accR[nt][r];
            *(f32x4*)(htout + ((size_t)b * T_LEN + t) * 64 + o0) = hv;
        }
    }
    if (DO_SKIP) {
#pragma unroll
        for (int mi = 0; mi < 4; ++mi) {
#pragma unroll
            for (int nt = 0; nt < 4; ++nt) {
                int t = t0 + nt * 16 + lo;
                int p0 = (w * 4 + mi) * 16 + hi * 4;
#pragma unroll
                for (int r = 0; r < 4; ++r) {
                    float* sp = &skipsum[((size_t)b * 256 + p0 + r) * T_LEN + t];
                    float v = accS[mi][nt][r];
                    if (first) *sp = v; else *sp = *sp + v;
                }
            }
        }
    }
}

// ================= fused skip-reduce + pp1 + pp2 (T14 async-staged z dbuf) ===========
__global__ __launch_bounds__(256) void skip_post(
    const u16* __restrict__ zT, const u16* __restrict__ swpAll,
    const float* __restrict__ sbsum,
    const u16* __restrict__ pp1p, const float* __restrict__ pp1b,
    const u16* __restrict__ pp2p, const float* __restrict__ pp2b,
    float* __restrict__ out)
{
    __shared__ u16 lds[64 * 256];     // 32 KB; phase1: two 8KB z bufs; phase2: sl
    int tid = threadIdx.x;
    int w = tid >> 6, l = tid & 63;
    int lo = l & 15, hi = l >> 4;
    int wg = xcd_swz(blockIdx.x);
    int b = wg >> 8, t0 = (wg & 255) * 64;

    // staging identity: 2 chunks (16B) per lane
    int idx0 = w * 128 + l, idx1 = idx0 + 64;
    int row0 = idx0 >> 3, s0 = idx0 & 7;
    int row1 = idx1 >> 3, s1 = idx1 & 7;
    size_t goff0 = ((size_t)t0 + row0) * 64 + s0 * 8;
    size_t goff1 = ((size_t)t0 + row1) * 64 + s1 * 8;
    int loff0 = row0 * 64 + ((s0 ^ (row0 & 7)) << 3);
    int loff1 = row1 * 64 + ((s1 ^ (row1 & 7)) << 3);

    f32x4 acc[4][4];
#pragma unroll
    for (int mi = 0; mi < 4; ++mi) {
        f32x4 iS;
#pragma unroll
        for (int r = 0; r < 4; ++r) iS[r] = sbsum[(w * 4 + mi) * 16 + hi * 4 + r];
#pragma unroll
        for (int nt = 0; nt < 4; ++nt) acc[mi][nt] = iS;
    }

    // prologue: layer 0 -> bufA; layer 1 -> regs
    {
        const u16* z0 = zT + (size_t)b * T_LEN * 64;
        uint4 p0 = *(const uint4*)(z0 + goff0);
        uint4 p1_ = *(const uint4*)(z0 + goff1);
        *(uint4*)(&lds[loff0]) = p0;
        *(uint4*)(&lds[loff1]) = p1_;
    }
    const u16* z1 = zT + ((size_t)4 + b) * T_LEN * 64;
    uint4 r0 = *(const uint4*)(z1 + goff0);
    uint4 r1 = *(const uint4*)(z1 + goff1);
    __syncthreads();

    const uint4* swv = (const uint4*)swpAll;
    int cur = 0;
    for (int i = 0; i < L_LAYERS; ++i) {
        // write staged regs (layer i+1) into other buf; issue load of layer i+2
        if (i + 1 < L_LAYERS) {
            u16* zn_ = lds + ((cur ^ 1) << 12);
            *(uint4*)(&zn_[loff0]) = r0;
            *(uint4*)(&zn_[loff1]) = r1;
            if (i + 2 < L_LAYERS) {
                const u16* zn = zT + ((size_t)((i + 2) * 4 + b)) * T_LEN * 64;
                r0 = *(const uint4*)(zn + goff0);
                r1 = *(const uint4*)(zn + goff1);
            }
        }
        // MFMA layer i from lds buf cur
        const u16* zc = lds + (cur << 12);
#pragma unroll
        for (int kk = 0; kk < 2; ++kk) {
            uint4 a[4];
#pragma unroll
            for (int mi = 0; mi < 4; ++mi)
                a[mi] = swv[((i * 16 + w * 4 + mi) * 2 + kk) * 64 + l];
#pragma unroll
            for (int nt = 0; nt < 4; ++nt) {
                int n = nt * 16 + lo;
                int s = (kk * 4 + hi) ^ (n & 7);
                uint4 bz = *(const uint4*)(&zc[n * 64 + (s << 3)]);
#pragma unroll
                for (int mi = 0; mi < 4; ++mi)
                    acc[mi][nt] = mfma16(a[mi], bz, acc[mi][nt]);
            }
        }
        __syncthreads();
        cur ^= 1;
    }

    // ---- relu(skip) -> sl (bf16, swizzled) ----
#pragma unroll
    for (int mi = 0; mi < 4; ++mi) {
#pragma unroll
        for (int nt = 0; nt < 4; ++nt) {
            int n = nt * 16 + lo;
            int k0 = (w * 4 + mi) * 16 + hi * 4;
            int col = k0 ^ ((n & 15) << 3);
            float v0 = acc[mi][nt][0], v1 = acc[mi][nt][1], v2 = acc[mi][nt][2], v3 = acc[mi][nt][3];
            v0 = v0 > 0.f ? v0 : 0.f; v1 = v1 > 0.f ? v1 : 0.f;
            v2 = v2 > 0.f ? v2 : 0.f; v3 = v3 > 0.f ? v3 : 0.f;
            *(unsigned*)(&lds[n * 256 + col]) = cvt2(v0, v1);
            *(unsigned*)(&lds[n * 256 + col + 2]) = cvt2(v2, v3);
        }
    }
    __syncthreads();

    // ---- pp1 ----
    f32x4 u[4][4];
#pragma unroll
    for (int mi = 0; mi < 4; ++mi) {
        f32x4 iU;
#pragma unroll
        for (int r = 0; r < 4; ++r) iU[r] = pp1b[(w * 4 + mi) * 16 + hi * 4 + r];
#pragma unroll
        for (int nt = 0; nt < 4; ++nt) u[mi][nt] = iU;
    }
    {
        const uint4* p1v = (const uint4*)pp1p;
#pragma unroll
        for (int kk = 0; kk < 8; ++kk) {
            uint4 a[4];
#pragma unroll
            for (int mi = 0; mi < 4; ++mi)
                a[mi] = p1v[((w * 4 + mi) * 8 + kk) * 64 + l];
#pragma unroll
            for (int nt = 0; nt < 4; ++nt) {
                int n = nt * 16 + lo;
                int kb = kk * 32 + hi * 8;
                uint4 bz = *(const uint4*)(&lds[n * 256 + (kb ^ ((n & 15) << 3))]);
#pragma unroll
                for (int mi = 0; mi < 4; ++mi)
                    u[mi][nt] = mfma16(a[mi], bz, u[mi][nt]);
            }
        }
    }
    __syncthreads();
#pragma unroll
    for (int mi = 0; mi < 4; ++mi) {
#pragma unroll
        for (int nt = 0; nt < 4; ++nt) {
            int n = nt * 16 + lo;
            int k0 = (w * 4 + mi) * 16 + hi * 4;
            int col = k0 ^ ((n & 15) << 3);
            float v0 = u[mi][nt][0], v1 = u[mi][nt][1], v2 = u[mi][nt][2], v3 = u[mi][nt][3];
            v0 = v0 > 0.f ? v0 : 0.f; v1 = v1 > 0.f ? v1 : 0.f;
            v2 = v2 > 0.f ? v2 : 0.f; v3 = v3 > 0.f ? v3 : 0.f;
            *(unsigned*)(&lds[n * 256 + col]) = cvt2(v0, v1);
            *(unsigned*)(&lds[n * 256 + col + 2]) = cvt2(v2, v3);
        }
    }
    __syncthreads();

    // ---- pp2 ----
    f32x4 vv[4][4];
#pragma unroll
    for (int mi = 0; mi < 4; ++mi) {
        f32x4 iV;
#pragma unroll
        for (int r = 0; r < 4; ++r) iV[r] = pp2b[(w * 4 + mi) * 16 + hi * 4 + r];
#pragma unroll
        for (int nt = 0; nt < 4; ++nt) vv[mi][nt] = iV;
    }
    {
        const uint4* p2v = (const uint4*)pp2p;
#pragma unroll
        for (int kk = 0; kk < 8; ++kk) {
            uint4 a[4];
#pragma unroll
            for (int mi = 0; mi < 4; ++mi)
                a[mi] = p2v[((w * 4 + mi) * 8 + kk) * 64 + l];
#pragma unroll
            for (int nt = 0; nt < 4; ++nt) {
                int n = nt * 16 + lo;
                int kb = kk * 32 + hi * 8;
                uint4 bz = *(const uint4*)(&lds[n * 256 + (kb ^ ((n & 15) << 3))]);
#pragma unroll
                for (int mi = 0; mi < 4; ++mi)
                    vv[mi][nt] = mfma16(a[mi], bz, vv[mi][nt]);
            }
        }
    }
#pragma unroll
    for (int mi = 0; mi < 4; ++mi) {
#pragma unroll
        for (int nt = 0; nt < 4; ++nt) {
            int t = t0 + nt * 16 + lo;
            int p0 = (w * 4 + mi) * 16 + hi * 4;
#pragma unroll
            for (int r = 0; r < 4; ++r)
                out[((size_t)b * 256 + p0 + r) * T_LEN + t] = vv[mi][nt][r];
        }
    }
}

// ================= plan C post (fp32 skipsum fallback) =================
__global__ __launch_bounds__(256) void post_mfma(
    const float* __restrict__ skipsum,
    const u16* __restrict__ pp1p, const float* __restrict__ pp1b,
    const u16* __restrict__ pp2p, const float* __restrict__ pp2b,
    float* __restrict__ out)
{
    __shared__ u16 sl[64 * 256];
    int tid = threadIdx.x;
    int w = tid >> 6, l = tid & 63;
    int lo = l & 15, hi = l >> 4;
    int nblk = T_LEN / 64;
    int b = blockIdx.x / nblk, t0 = (blockIdx.x % nblk) * 64;

#pragma unroll
    for (int mi = 0; mi < 4; ++mi) {
#pragma unroll
        for (int nt = 0; nt < 4; ++nt) {
            int n = nt * 16 + lo;
            int t = t0 + n;
            int p0 = (w * 4 + mi) * 16 + hi * 4;
            float v[4];
#pragma unroll
            for (int r = 0; r < 4; ++r) {
                float s = skipsum[((size_t)b * 256 + p0 + r) * T_LEN + t];
                v[r] = s > 0.f ? s : 0.f;
            }
            int col = p0 ^ ((n & 15) << 3);
            *(unsigned*)(&sl[n * 256 + col]) = cvt2(v[0], v[1]);
            *(unsigned*)(&sl[n * 256 + col + 2]) = cvt2(v[2], v[3]);
        }
    }
    __syncthreads();

    f32x4 u[4][4];
#pragma unroll
    for (int mi = 0; mi < 4; ++mi) {
        f32x4 iU;
#pragma unroll
        for (int r = 0; r < 4; ++r) iU[r] = pp1b[(w * 4 + mi) * 16 + hi * 4 + r];
#pragma unroll
        for (int nt = 0; nt < 4; ++nt) u[mi][nt] = iU;
    }
    {
        const uint4* p1v = (const uint4*)pp1p;
#pragma unroll
        for (int kk = 0; kk < 8; ++kk) {
            uint4 a[4];
#pragma unroll
            for (int mi = 0; mi < 4; ++mi)
                a[mi] = p1v[((w * 4 + mi) * 8 + kk) * 64 + l];
#pragma unroll
            for (int nt = 0; nt < 4; ++nt) {
                int n = nt * 16 + lo;
                int kb = kk * 32 + hi * 8;
                uint4 bz = *(const uint4*)(&sl[n * 256 + (kb ^ ((n & 15) << 3))]);
#pragma unroll
                for (int mi = 0; mi < 4; ++mi)
                    u[mi][nt] = mfma16(a[mi], bz, u[mi][nt]);
            }
        }
    }
    __syncthreads();
#pragma unroll
    for (int mi = 0; mi < 4; ++mi) {
#pragma unroll
        for (int nt = 0; nt < 4; ++nt) {
            int n = nt * 16 + lo;
            int k0 = (w * 4 + mi) * 16 + hi * 4;
            int col = k0 ^ ((n & 15) << 3);
            float v0 = u[mi][nt][0], v1 = u[mi][nt][1], v2 = u[mi][nt][2], v3 = u[mi][nt][3];
            v0 = v0 > 0.f ? v0 : 0.f; v1 = v1 > 0.f ? v1 : 0.f;
            v2 = v2 > 0.f ? v2 : 0.f; v3 = v3 > 0.f ? v3 : 0.f;
            *(unsigned*)(&sl[n * 256 + col]) = cvt2(v0, v1);
            *(unsigned*)(&sl[n * 256 + col + 2]) = cvt2(v2, v3);
        }
    }
    __syncthreads();

    f32x4 vv[4][4];
#pragma unroll
    for (int mi = 0; mi < 4; ++mi) {
        f32x4 iV;
#pragma unroll
        for (int r = 0; r < 4; ++r) iV[r] = pp2b[(w * 4 + mi) * 16 + hi * 4 + r];
#pragma unroll
        for (int nt = 0; nt < 4; ++nt) vv[mi][nt] = iV;
    }
    {
        const uint4* p2v = (const uint4*)pp2p;
#pragma unroll
        for (int kk = 0; kk < 8; ++kk) {
            uint4 a[4];
#pragma unroll
            for (int mi = 0; mi < 4; ++mi)
                a[mi] = p2v[((w * 4 + mi) * 8 + kk) * 64 + l];
#pragma unroll
            for (int nt = 0; nt < 4; ++nt) {
                int n = nt * 16 + lo;
                int kb = kk * 32 + hi * 8;
                uint4 bz = *(const uint4*)(&sl[n * 256 + (kb ^ ((n & 15) << 3))]);
#pragma unroll
                for (int mi = 0; mi < 4; ++mi)
                    vv[mi][nt] = mfma16(a[mi], bz, vv[mi][nt]);
            }
        }
    }
#pragma unroll
    for (int mi = 0; mi < 4; ++mi) {
#pragma unroll
        for (int nt = 0; nt < 4; ++nt) {
            int t = t0 + nt * 16 + lo;
            int p0 = (w * 4 + mi) * 16 + hi * 4;
#pragma unroll
            for (int r = 0; r < 4; ++r)
                out[((size_t)b * 256 + p0 + r) * T_LEN + t] = vv[mi][nt][r];
        }
    }
}

// ================= launch =================
extern "C" void kernel_launch(void* const* d_in, const int* in_sizes, int n_in,
                              void* d_out, int out_size, void* d_ws, size_t ws_size,
                              hipStream_t stream)
{
    const float* x      = (const float*)d_in[0];
    const float* pre_w  = (const float*)d_in[1];
    const float* pre_b  = (const float*)d_in[2];
    const float* filt_w = (const float*)d_in[3];
    const float* filt_b = (const float*)d_in[4];
    const float* gate_w = (const float*)d_in[5];
    const float* gate_b = (const float*)d_in[6];
    const float* res_w  = (const float*)d_in[7];
    const float* res_b  = (const float*)d_in[8];
    const float* skip_w = (const float*)d_in[9];
    const float* skip_b = (const float*)d_in[10];
    const float* pp1_w  = (const float*)d_in[11];
    const float* pp1_b  = (const float*)d_in[12];
    const float* pp2_w  = (const float*)d_in[13];
    const float* pp2_b  = (const float*)d_in[14];
    float* outp = (float*)d_out;

    float* ht0 = outp;
    float* ht1 = outp + (size_t)4194304;

    const size_t ZT_BYTES   = (size_t)L_LAYERS * B_SZ * T_LEN * 64 * 2;   // 167,772,160
    const size_t SKIP_BYTES = (size_t)B_SZ * SKIP_C * T_LEN * 4;          // 67,108,864

    const bool useZ = ws_size >= ZT_BYTES + (size_t)2 * 1024 * 1024;

    char* ws = (char*)d_ws;
    u16*   zT      = (u16*)ws;
    float* skipsum = (float*)ws;
    size_t packoff = useZ ? ZT_BYTES : SKIP_BYTES;
    u16* w1p  = (u16*)(ws + packoff);
    u16* swp  = w1p + 327680;
    u16* rwp  = swp + 327680;
    u16* pp1p = rwp + 81920;
    u16* pp2p = pp1p + 65536;
    u16* prep = pp2p + 65536;
    float* sbsum = (float*)(prep + 16384);

    repack2<<<3457, 256, 0, stream>>>(filt_w, gate_w, skip_w, res_w, pp1_w, pp2_w, pre_w, skip_b,
                                      w1p, swp, rwp, pp1p, pp2p, prep, sbsum);

    pre_mfma<<<1024, 256, 0, stream>>>(x, prep, pre_b, ht0);

    const float* hi_ = ht0; float* ho_ = ht1;
    for (int i = 0; i < L_LAYERS; ++i) {
        int d = 1 << (i % 10);
        int first = (i == 0) ? 1 : 0;
        int last  = (i == L_LAYERS - 1) ? 1 : 0;
        if (useZ)
            layer_mfma<0><<<1024, 256, 0, stream>>>(
                hi_, ho_,
                zT + (size_t)i * 4194304, skipsum,
                w1p + (size_t)i * 16384, swp + (size_t)i * 16384, rwp + (size_t)i * 4096,
                filt_b + i * 64, gate_b + i * 64, skip_b + i * 256, res_b + i * 64,
                d, first, last);
        else
            layer_mfma<1><<<1024, 256, 0, stream>>>(
                hi_, ho_,
                zT, skipsum,
                w1p + (size_t)i * 16384, swp + (size_t)i * 16384, rwp + (size_t)i * 4096,
                filt_b + i * 64, gate_b + i * 64, skip_b + i * 256, res_b + i * 64,
                d, first, last);
        { const float* tf = hi_; hi_ = ho_; ho_ = (float*)tf; }
    }

    if (useZ)
        skip_post<<<1024, 256, 0, stream>>>(zT, swp, sbsum, pp1p, pp1_b, pp2p, pp2_b, outp);
    else
        post_mfma<<<1024, 256, 0, stream>>>(skipsum, pp1p, pp1_b, pp2p, pp2_b, outp);
}